// Round 1
// baseline (2366.425 us; speedup 1.0000x reference)
//
#include <hip/hip_runtime.h>
#include <hip/hip_bf16.h>

#define Bz 512
#define NF 512
#define TT 64
#define HIDZ 1024
#define LATZ 2

// output layout (floats)
static const size_t OFF_XAE   = 0;                                  // 512*512*64
static const size_t OFF_Y     = (size_t)Bz * NF * TT;               // 16777216
static const size_t OFF_DMD   = OFF_Y + (size_t)Bz * LATZ * TT;     // 16842752
static const size_t OFF_AE    = OFF_DMD + 1;                        // 16842753
static const size_t OFF_YPRED = OFF_AE + 1;                         // 16842754
static const size_t OFF_AMAT  = OFF_YPRED + (size_t)Bz * LATZ * TT; // 16908290
static const size_t OFF_PRED  = OFF_AMAT + (size_t)1024 * 1024;     // 17956866

// workspace layout (float offsets)
#define WS_G     0
#define WS_GINV  4096
#define WS_PROJ  8192
#define WS_P     16384     // 63*1024
#define WS_V0    81920     // 1024
#define WS_V1    83968     // 1024
#define WS_AM    131072    // 1024*1024 aligned copy of Amat

__device__ inline float blockReduceSum(float v) {
  __shared__ float sh[16];
  int lane = threadIdx.x & 63;
  int wid  = threadIdx.x >> 6;
#pragma unroll
  for (int off = 32; off > 0; off >>= 1) v += __shfl_down(v, off, 64);
  if (lane == 0) sh[wid] = v;
  __syncthreads();
  int nw = blockDim.x >> 6;
  v = (threadIdx.x < (unsigned)nw) ? sh[threadIdx.x] : 0.f;
  if (wid == 0) {
#pragma unroll
    for (int off = 8; off > 0; off >>= 1) v += __shfl_down(v, off, 64);
  }
  return v;
}

// init y = be2 broadcast; zero the three scalar loss slots
__global__ void k_init(float* __restrict__ y, const float* __restrict__ be2,
                       float* dmd, float* ae, float* pred) {
  int idx = blockIdx.x * 256 + threadIdx.x;          // 65536 total
  y[idx] = be2[(idx >> 6) & 1];
  if (idx == 0) { *dmd = 0.f; *ae = 0.f; *pred = 0.f; }
}

// GEMM1 fused: h = tanh(We1^T x_b + be1) per (b, 64-hh tile), then reduce into y via atomics
__global__ __launch_bounds__(256) void k_gemm1(const float* __restrict__ x,
                                               const float* __restrict__ We1,
                                               const float* __restrict__ be1,
                                               const float* __restrict__ We2,
                                               float* __restrict__ y_out) {
  __shared__ float Xs[32][64];
  __shared__ float Ws[32][64];
  __shared__ float ypart[2][64];
  int b = blockIdx.y, hh0 = blockIdx.x * 64;
  int tid = threadIdx.x;
  int tx = tid & 15, ty = tid >> 4;   // tx: t-group, ty: hh-group
  const float* xb = x + (size_t)b * NF * TT;
  float acc[4][4] = {};
  for (int k0 = 0; k0 < NF; k0 += 32) {
#pragma unroll
    for (int p = 0; p < 2; ++p) {
      int f = tid + p * 256;               // [0,512)
      int kk = f >> 4, q = (f & 15) * 4;
      *(float4*)&Xs[kk][q] = *(const float4*)&xb[(size_t)(k0 + kk) * TT + q];
      *(float4*)&Ws[kk][q] = *(const float4*)&We1[(size_t)(k0 + kk) * HIDZ + hh0 + q];
    }
    __syncthreads();
#pragma unroll
    for (int kk = 0; kk < 32; ++kk) {
      float4 av = *(float4*)&Ws[kk][ty * 4];
      float4 bv = *(float4*)&Xs[kk][tx * 4];
      acc[0][0] += av.x * bv.x; acc[0][1] += av.x * bv.y; acc[0][2] += av.x * bv.z; acc[0][3] += av.x * bv.w;
      acc[1][0] += av.y * bv.x; acc[1][1] += av.y * bv.y; acc[1][2] += av.y * bv.z; acc[1][3] += av.y * bv.w;
      acc[2][0] += av.z * bv.x; acc[2][1] += av.z * bv.y; acc[2][2] += av.z * bv.z; acc[2][3] += av.z * bv.w;
      acc[3][0] += av.w * bv.x; acc[3][1] += av.w * bv.y; acc[3][2] += av.w * bv.z; acc[3][3] += av.w * bv.w;
    }
    __syncthreads();
  }
  if (tid < 128) ypart[tid >> 6][tid & 63] = 0.f;
  __syncthreads();
  float c0[4] = {}, c1[4] = {};
#pragma unroll
  for (int i = 0; i < 4; ++i) {
    int hh = hh0 + ty * 4 + i;
    float bias = be1[hh];
    float w0 = We2[hh * LATZ + 0], w1 = We2[hh * LATZ + 1];
#pragma unroll
    for (int j = 0; j < 4; ++j) {
      float hval = tanhf(acc[i][j] + bias);
      c0[j] += hval * w0;
      c1[j] += hval * w1;
    }
  }
#pragma unroll
  for (int j = 0; j < 4; ++j) {
    atomicAdd(&ypart[0][tx * 4 + j], c0[j]);
    atomicAdd(&ypart[1][tx * 4 + j], c1[j]);
  }
  __syncthreads();
  if (tid < 128) {
    int l = tid >> 6, t = tid & 63;
    atomicAdd(&y_out[((size_t)b * LATZ + l) * TT + t], ypart[l][t]);
  }
}

// GEMM4 fused: hd computed on the fly from y; x_ae = hd^T-style tile GEMM + bd2
__global__ __launch_bounds__(256) void k_gemm4(const float* __restrict__ y,
                                               const float* __restrict__ Wd1,
                                               const float* __restrict__ bd1,
                                               const float* __restrict__ Wd2,
                                               const float* __restrict__ bd2,
                                               float* __restrict__ xae) {
  __shared__ float Hs[32][64];   // hd tile [kk][t]
  __shared__ float Ws[32][64];   // Wd2 tile [kk][n]
  __shared__ float ys[2][64];
  int b = blockIdx.y, n0 = blockIdx.x * 64;
  int tid = threadIdx.x, tx = tid & 15, ty = tid >> 4;
  if (tid < 128) ys[tid >> 6][tid & 63] = y[((size_t)b * LATZ + (tid >> 6)) * TT + (tid & 63)];
  __syncthreads();
  float acc[4][4] = {};
  for (int k0 = 0; k0 < HIDZ; k0 += 32) {
#pragma unroll
    for (int p = 0; p < 8; ++p) {
      int f = tid + p * 256;              // [0,2048)
      int kk = f >> 6, t = f & 63;
      int h = k0 + kk;
      Hs[kk][t] = tanhf(ys[0][t] * Wd1[h] + ys[1][t] * Wd1[HIDZ + h] + bd1[h]);
    }
#pragma unroll
    for (int p = 0; p < 2; ++p) {
      int f = tid + p * 256;
      int kk = f >> 4, q = (f & 15) * 4;
      *(float4*)&Ws[kk][q] = *(const float4*)&Wd2[(size_t)(k0 + kk) * NF + n0 + q];
    }
    __syncthreads();
#pragma unroll
    for (int kk = 0; kk < 32; ++kk) {
      float4 av = *(float4*)&Ws[kk][ty * 4];
      float4 bv = *(float4*)&Hs[kk][tx * 4];
      acc[0][0] += av.x * bv.x; acc[0][1] += av.x * bv.y; acc[0][2] += av.x * bv.z; acc[0][3] += av.x * bv.w;
      acc[1][0] += av.y * bv.x; acc[1][1] += av.y * bv.y; acc[1][2] += av.y * bv.z; acc[1][3] += av.y * bv.w;
      acc[2][0] += av.z * bv.x; acc[2][1] += av.z * bv.y; acc[2][2] += av.z * bv.z; acc[2][3] += av.z * bv.w;
      acc[3][0] += av.w * bv.x; acc[3][1] += av.w * bv.y; acc[3][2] += av.w * bv.z; acc[3][3] += av.w * bv.w;
    }
    __syncthreads();
  }
#pragma unroll
  for (int i = 0; i < 4; ++i) {
    int n = n0 + ty * 4 + i;
    float bias = bd2[n];
    float4 o;
    o.x = acc[i][0] + bias; o.y = acc[i][1] + bias; o.z = acc[i][2] + bias; o.w = acc[i][3] + bias;
    *(float4*)&xae[((size_t)b * NF + n) * TT + tx * 4] = o;
  }
}

// G = Y-^T Y-  (63x63), Y- = yw[:, 0:63], yw = y viewed (1024, 64)
__global__ __launch_bounds__(1024) void k_G(const float* __restrict__ y, float* __restrict__ G) {
  __shared__ float ys[16][64];
  int tid = threadIdx.x;
  float acc[4] = {};
  for (int r0 = 0; r0 < 1024; r0 += 16) {
    __syncthreads();
    { int rr = tid >> 6, c = tid & 63; ys[rr][c] = y[(size_t)(r0 + rr) * 64 + c]; }
    __syncthreads();
#pragma unroll
    for (int p = 0; p < 4; ++p) {
      int pair = tid + p * 1024;
      if (pair < 3969) {
        int i = pair / 63, j = pair % 63;
        float s = 0.f;
#pragma unroll
        for (int rr = 0; rr < 16; ++rr) s += ys[rr][i] * ys[rr][j];
        acc[p] += s;
      }
    }
  }
#pragma unroll
  for (int p = 0; p < 4; ++p) {
    int pair = tid + p * 1024;
    if (pair < 3969) G[pair] = acc[p];
  }
}

// Gauss-Jordan inverse of SPD 63x63 in f64 (augmented [G|I] in LDS)
__global__ __launch_bounds__(256) void k_inv(const float* __restrict__ G, float* __restrict__ Ginv) {
  __shared__ double A[63][126];
  __shared__ double colk[63];
  int tid = threadIdx.x;
  for (int f = tid; f < 63 * 126; f += 256) {
    int i = f / 126, j = f % 126;
    A[i][j] = (j < 63) ? (double)G[i * 63 + j] : ((j - 63 == i) ? 1.0 : 0.0);
  }
  __syncthreads();
  for (int k = 0; k < 63; ++k) {
    double piv = A[k][k];
    if (tid < 63) colk[tid] = A[tid][k];
    __syncthreads();
    double rp = 1.0 / piv;
    for (int j = tid; j < 126; j += 256) A[k][j] *= rp;
    __syncthreads();
    for (int f = tid; f < 63 * 126; f += 256) {
      int i = f / 126, j = f % 126;
      if (i != k) A[i][j] -= colk[i] * A[k][j];
    }
    __syncthreads();
  }
  for (int f = tid; f < 63 * 63; f += 256) {
    int i = f / 63, j = f % 63;
    Ginv[f] = (float)A[i][63 + j];
  }
}

// P = Ginv * Y-^T  (63 x 1024), P[i*1024 + r]
__global__ __launch_bounds__(256) void k_P(const float* __restrict__ y,
                                           const float* __restrict__ Ginv,
                                           float* __restrict__ P) {
  __shared__ float ys[64][65];
  int r0 = blockIdx.x * 64, tid = threadIdx.x;
#pragma unroll
  for (int p = 0; p < 16; ++p) {
    int f = tid + p * 256;
    ys[f >> 6][f & 63] = y[(size_t)(r0 + (f >> 6)) * 64 + (f & 63)];
  }
  __syncthreads();
#pragma unroll
  for (int p = 0; p < 16; ++p) {
    int o = tid + p * 256;
    if (o < 4032) {
      int i = o >> 6, rr = o & 63;
      float s = 0.f;
#pragma unroll
      for (int j = 0; j < 63; ++j) s += Ginv[i * 63 + j] * ys[rr][j];
      P[(size_t)i * 1024 + r0 + rr] = s;
    }
  }
}

// proj = I - P @ Y-   (63x63)
__global__ __launch_bounds__(1024) void k_proj(const float* __restrict__ y,
                                               const float* __restrict__ P,
                                               float* __restrict__ proj) {
  __shared__ float ys[16][64];
  __shared__ float ps[63][16];
  int tid = threadIdx.x;
  float acc[4] = {};
  for (int r0 = 0; r0 < 1024; r0 += 16) {
    __syncthreads();
    { int rr = tid >> 6, c = tid & 63; ys[rr][c] = y[(size_t)(r0 + rr) * 64 + c]; }
    if (tid < 1008) { int i = tid >> 4, rr = tid & 15; ps[i][rr] = P[(size_t)i * 1024 + r0 + rr]; }
    __syncthreads();
#pragma unroll
    for (int p = 0; p < 4; ++p) {
      int pair = tid + p * 1024;
      if (pair < 3969) {
        int i = pair / 63, j = pair % 63;
        float s = 0.f;
#pragma unroll
        for (int rr = 0; rr < 16; ++rr) s += ps[i][rr] * ys[rr][j];
        acc[p] += s;
      }
    }
  }
#pragma unroll
  for (int p = 0; p < 4; ++p) {
    int pair = tid + p * 1024;
    if (pair < 3969) {
      int i = pair / 63, j = pair % 63;
      proj[pair] = ((i == j) ? 1.f : 0.f) - acc[p];
    }
  }
}

// Amat = Y+ @ P  (1024x1024): scalar stores to d_out (8B-aligned base), plus aligned ws copy
__global__ __launch_bounds__(256) void k_Amat(const float* __restrict__ y,
                                              const float* __restrict__ P,
                                              float* __restrict__ amat_out,
                                              float* __restrict__ a_ws) {
  __shared__ float Yp[64][65];
  __shared__ float Ps[63][64];
  int r0 = blockIdx.x * 64, p0 = blockIdx.y * 64;
  int tid = threadIdx.x, tx = tid & 15, ty = tid >> 4;
#pragma unroll
  for (int p = 0; p < 16; ++p) {
    int f = tid + p * 256;
    Yp[f >> 6][f & 63] = y[(size_t)(p0 + (f >> 6)) * 64 + (f & 63)];
  }
#pragma unroll
  for (int p = 0; p < 16; ++p) {
    int f = tid + p * 256;
    if (f < 4032) {
      int j = f >> 6, rr = f & 63;
      Ps[j][rr] = P[(size_t)j * 1024 + r0 + rr];
    }
  }
  __syncthreads();
  float acc[4][4] = {};
  for (int j = 0; j < 63; ++j) {
    float a0 = Yp[ty * 4 + 0][j + 1];
    float a1 = Yp[ty * 4 + 1][j + 1];
    float a2 = Yp[ty * 4 + 2][j + 1];
    float a3 = Yp[ty * 4 + 3][j + 1];
    float4 bv = *(float4*)&Ps[j][tx * 4];
    acc[0][0] += a0 * bv.x; acc[0][1] += a0 * bv.y; acc[0][2] += a0 * bv.z; acc[0][3] += a0 * bv.w;
    acc[1][0] += a1 * bv.x; acc[1][1] += a1 * bv.y; acc[1][2] += a1 * bv.z; acc[1][3] += a1 * bv.w;
    acc[2][0] += a2 * bv.x; acc[2][1] += a2 * bv.y; acc[2][2] += a2 * bv.z; acc[2][3] += a2 * bv.w;
    acc[3][0] += a3 * bv.x; acc[3][1] += a3 * bv.y; acc[3][2] += a3 * bv.z; acc[3][3] += a3 * bv.w;
  }
#pragma unroll
  for (int i = 0; i < 4; ++i) {
#pragma unroll
    for (int jj = 0; jj < 4; ++jj) {
      size_t idx = (size_t)(p0 + ty * 4 + i) * 1024 + r0 + tx * 4 + jj;
      amat_out[idx] = acc[i][jj];
      a_ws[idx] = acc[i][jj];
    }
  }
}

// dmd_loss = sum((Y+ @ proj)^2)
__global__ __launch_bounds__(256) void k_dmdloss(const float* __restrict__ y,
                                                 const float* __restrict__ proj,
                                                 float* __restrict__ out_dmd) {
  __shared__ float ps[3969];
  int tid = threadIdx.x;
  for (int f = tid; f < 3969; f += 256) ps[f] = proj[f];
  __syncthreads();
  int p = blockIdx.x * 256 + tid;      // row of Y+
  float yp[63];
#pragma unroll
  for (int k = 0; k < 63; ++k) yp[k] = y[(size_t)p * 64 + k + 1];
  float accv = 0.f;
  for (int j = 0; j < 63; ++j) {
    float s = 0.f;
#pragma unroll
    for (int k = 0; k < 63; ++k) s += yp[k] * ps[k * 63 + j];
    accv += s * s;
  }
  float tot = blockReduceSum(accv);
  if (tid == 0) atomicAdd(out_dmd, tot);
}

// v0 = y0 = yw[:, 0]
__global__ void k_y0(const float* __restrict__ y, float* __restrict__ v0) {
  int r = threadIdx.x + blockIdx.x * 1024;
  v0[r] = y[(size_t)r * 64];
}

// vout = A @ v; also y_pred[:, t] = vout
__global__ __launch_bounds__(256) void k_matvec(const float* __restrict__ A,
                                                const float* __restrict__ v,
                                                float* __restrict__ vout,
                                                float* __restrict__ ypred, int t) {
  int tid = threadIdx.x;
  int ry = tid >> 4, cx = tid & 15;
  int r = blockIdx.x * 16 + ry;
  const float* Ar = A + (size_t)r * 1024;
  float s = 0.f;
  for (int c0 = cx * 4; c0 < 1024; c0 += 64) {
    float4 a = *(const float4*)&Ar[c0];
    float4 vv = *(const float4*)&v[c0];
    s += a.x * vv.x + a.y * vv.y + a.z * vv.z + a.w * vv.w;
  }
#pragma unroll
  for (int off = 8; off > 0; off >>= 1) s += __shfl_down(s, off, 16);
  if (cx == 0) {
    vout[r] = s;
    ypred[(size_t)r * 64 + t] = s;
  }
}

// pred_loss = mean((y_pred - y)^2)
__global__ __launch_bounds__(256) void k_predloss(const float* __restrict__ y,
                                                  const float* __restrict__ ypred,
                                                  float* __restrict__ outp) {
  int i = blockIdx.x * 256 + threadIdx.x;   // 65536 total
  float d = ypred[i] - y[i];
  float tot = blockReduceSum(d * d);
  if (threadIdx.x == 0) atomicAdd(outp, tot * (1.f / 65536.f));
}

// ae_loss = mean((x[:,:,0] - x_ae[:,:,0])^2)
__global__ __launch_bounds__(256) void k_aeloss(const float* __restrict__ x,
                                                const float* __restrict__ xae,
                                                float* __restrict__ outp) {
  int i = blockIdx.x * 256 + threadIdx.x;   // 262144 total
  float d = x[(size_t)i * 64] - xae[(size_t)i * 64];
  float tot = blockReduceSum(d * d);
  if (threadIdx.x == 0) atomicAdd(outp, tot * (1.f / 262144.f));
}

extern "C" void kernel_launch(void* const* d_in, const int* in_sizes, int n_in,
                              void* d_out, int out_size, void* d_ws, size_t ws_size,
                              hipStream_t stream) {
  (void)in_sizes; (void)n_in; (void)out_size; (void)ws_size;
  const float* x   = (const float*)d_in[0];
  const float* We1 = (const float*)d_in[1];
  const float* be1 = (const float*)d_in[2];
  const float* We2 = (const float*)d_in[3];
  const float* be2 = (const float*)d_in[4];
  const float* Wd1 = (const float*)d_in[5];
  const float* bd1 = (const float*)d_in[6];
  const float* Wd2 = (const float*)d_in[7];
  const float* bd2 = (const float*)d_in[8];
  float* out = (float*)d_out;
  float* wsf = (float*)d_ws;

  float* y_out = out + OFF_Y;

  k_init<<<256, 256, 0, stream>>>(y_out, be2, out + OFF_DMD, out + OFF_AE, out + OFF_PRED);
  k_gemm1<<<dim3(16, Bz), 256, 0, stream>>>(x, We1, be1, We2, y_out);
  k_gemm4<<<dim3(8, Bz), 256, 0, stream>>>(y_out, Wd1, bd1, Wd2, bd2, out + OFF_XAE);
  k_G<<<1, 1024, 0, stream>>>(y_out, wsf + WS_G);
  k_inv<<<1, 256, 0, stream>>>(wsf + WS_G, wsf + WS_GINV);
  k_P<<<16, 256, 0, stream>>>(y_out, wsf + WS_GINV, wsf + WS_P);
  k_proj<<<1, 1024, 0, stream>>>(y_out, wsf + WS_P, wsf + WS_PROJ);
  k_Amat<<<dim3(16, 16), 256, 0, stream>>>(y_out, wsf + WS_P, out + OFF_AMAT, wsf + WS_AM);
  k_dmdloss<<<4, 256, 0, stream>>>(y_out, wsf + WS_PROJ, out + OFF_DMD);
  k_y0<<<1, 1024, 0, stream>>>(y_out, wsf + WS_V0);
  for (int t = 0; t < 64; ++t) {
    const float* vin = wsf + ((t & 1) ? WS_V1 : WS_V0);
    float* vout = wsf + ((t & 1) ? WS_V0 : WS_V1);
    k_matvec<<<64, 256, 0, stream>>>(wsf + WS_AM, vin, vout, out + OFF_YPRED, t);
  }
  k_predloss<<<256, 256, 0, stream>>>(y_out, out + OFF_YPRED, out + OFF_PRED);
  k_aeloss<<<1024, 256, 0, stream>>>(x, out + OFF_XAE, out + OFF_AE);
}

// Round 2
// 1715.587 us; speedup vs baseline: 1.3794x; 1.3794x over previous
//
#include <hip/hip_runtime.h>
#include <hip/hip_bf16.h>

#define Bz 512
#define NF 512
#define TT 64
#define HIDZ 1024
#define LATZ 2

// output layout (floats)
static const size_t OFF_XAE   = 0;                                  // 512*512*64
static const size_t OFF_Y     = (size_t)Bz * NF * TT;               // 16777216
static const size_t OFF_DMD   = OFF_Y + (size_t)Bz * LATZ * TT;     // 16842752
static const size_t OFF_AE    = OFF_DMD + 1;                        // 16842753
static const size_t OFF_YPRED = OFF_AE + 1;                         // 16842754
static const size_t OFF_AMAT  = OFF_YPRED + (size_t)Bz * LATZ * TT; // 16908290
static const size_t OFF_PRED  = OFF_AMAT + (size_t)1024 * 1024;     // 17956866

// workspace layout (float offsets)
#define WS_G     0
#define WS_GINV  4096
#define WS_PROJ  8192
#define WS_P     16384     // 63*1024
#define WS_V0    81920     // 1024
#define WS_V1    83968     // 1024
#define WS_AM    131072    // 1024*1024 aligned copy of Amat
#define WS_YP    1179648   // 8*512*2*64 y partials (deterministic reduce)
#define WS_WD2T  1703936   // 1 MB: Wd2 as bf16 MFMA A-fragment layout (ushort)

typedef __attribute__((ext_vector_type(8))) short bf16x8;
typedef __attribute__((ext_vector_type(4))) float f32x4;

__device__ __forceinline__ unsigned short f2bf(float f) {
  unsigned u = __float_as_uint(f);
  unsigned r = (u + 0x7fffu + ((u >> 16) & 1u)) >> 16;
  return (unsigned short)r;
}

__device__ inline float blockReduceSum(float v) {
  __shared__ float sh[16];
  int lane = threadIdx.x & 63;
  int wid  = threadIdx.x >> 6;
#pragma unroll
  for (int off = 32; off > 0; off >>= 1) v += __shfl_down(v, off, 64);
  if (lane == 0) sh[wid] = v;
  __syncthreads();
  int nw = blockDim.x >> 6;
  v = (threadIdx.x < (unsigned)nw) ? sh[threadIdx.x] : 0.f;
  if (wid == 0) {
#pragma unroll
    for (int off = 8; off > 0; off >>= 1) v += __shfl_down(v, off, 64);
  }
  return v;
}

// zero the three scalar loss slots
__global__ void k_init(float* dmd, float* ae, float* pred) {
  if (threadIdx.x == 0) { *dmd = 0.f; *ae = 0.f; *pred = 0.f; }
}

// GEMM1: h = tanh(We1^T x + be1) for a 128h x 64t x 2b tile, reduce with We2
// into deterministic per-hblock partials in ws. f32 math throughout (y feeds
// the A^64 power chain; bf16 here would amplify).
__global__ __launch_bounds__(256) void k_gemm1(const float* __restrict__ x,
                                               const float* __restrict__ We1,
                                               const float* __restrict__ be1,
                                               const float* __restrict__ We2,
                                               float* __restrict__ ypartial) {
  __shared__ float Ws[32][128];
  __shared__ float Xs[2][32][64];
  __shared__ float part[16][2][2][64];
  int h0 = blockIdx.x * 128, b0 = blockIdx.y * 2;
  int hb = blockIdx.x;
  int tid = threadIdx.x, tx = tid & 15, ty = tid >> 4;
  float acc[2][8][4] = {};
  for (int k0 = 0; k0 < NF; k0 += 32) {
#pragma unroll
    for (int p = 0; p < 4; ++p) {
      int s = tid + p * 256;                       // [0,1024)
      int kk = s >> 5, h4 = (s & 31) * 4;
      *(float4*)&Ws[kk][h4] = *(const float4*)&We1[(size_t)(k0 + kk) * HIDZ + h0 + h4];
      int bh = s >> 9, r2 = s & 511, kk2 = r2 >> 4, q2 = (r2 & 15) * 4;
      *(float4*)&Xs[bh][kk2][q2] = *(const float4*)&x[((size_t)(b0 + bh) * NF + k0 + kk2) * TT + q2];
    }
    __syncthreads();
#pragma unroll
    for (int kk = 0; kk < 32; ++kk) {
      float a[8], xb[2][4];
      *(float4*)&a[0] = *(float4*)&Ws[kk][ty * 8];
      *(float4*)&a[4] = *(float4*)&Ws[kk][ty * 8 + 4];
      *(float4*)&xb[0][0] = *(float4*)&Xs[0][kk][tx * 4];
      *(float4*)&xb[1][0] = *(float4*)&Xs[1][kk][tx * 4];
#pragma unroll
      for (int bh = 0; bh < 2; ++bh)
#pragma unroll
        for (int i = 0; i < 8; ++i)
#pragma unroll
          for (int j = 0; j < 4; ++j) acc[bh][i][j] += a[i] * xb[bh][j];
    }
    __syncthreads();
  }
  // epilogue: tanh + We2 reduce, deterministic tree via LDS
  float c0[2][4] = {}, c1[2][4] = {};
#pragma unroll
  for (int i = 0; i < 8; ++i) {
    int h = h0 + ty * 8 + i;
    float bias = be1[h];
    float w0 = We2[h * LATZ + 0], w1 = We2[h * LATZ + 1];
#pragma unroll
    for (int bh = 0; bh < 2; ++bh)
#pragma unroll
      for (int j = 0; j < 4; ++j) {
        float hv = tanhf(acc[bh][i][j] + bias);
        c0[bh][j] += hv * w0;
        c1[bh][j] += hv * w1;
      }
  }
#pragma unroll
  for (int bh = 0; bh < 2; ++bh)
#pragma unroll
    for (int j = 0; j < 4; ++j) {
      part[ty][bh][0][tx * 4 + j] = c0[bh][j];
      part[ty][bh][1][tx * 4 + j] = c1[bh][j];
    }
  __syncthreads();
  {
    int bh = tid >> 7, l = (tid >> 6) & 1, t = tid & 63;
    float s = 0.f;
#pragma unroll
    for (int ty2 = 0; ty2 < 16; ++ty2) s += part[ty2][bh][l][t];
    ypartial[(((size_t)hb * Bz + b0 + bh) * LATZ + l) * TT + t] = s;
  }
}

// y = be2 + sum of 8 h-block partials (fixed order -> deterministic)
__global__ void k_yred(const float* __restrict__ yp, const float* __restrict__ be2,
                       float* __restrict__ y) {
  int idx = blockIdx.x * 256 + threadIdx.x;   // 65536
  int t = idx & 63, l = (idx >> 6) & 1, b = idx >> 7;
  float s = be2[l];
#pragma unroll
  for (int hb = 0; hb < 8; ++hb) s += yp[(((size_t)hb * Bz + b) * LATZ + l) * TT + t];
  y[idx] = s;
}

// Wd2 (f32 [k=1024][n=512]) -> bf16 MFMA A-fragment layout:
// 16B slot s = (kt*32 + mf)*64 + l, element e: A[m=mf*16+(l&15)][k=kt*32+(l>>4)*8+e] = Wd2[k][n=m]
__global__ void k_wd2t(const float* __restrict__ Wd2, unsigned short* __restrict__ at) {
  int s = blockIdx.x * 256 + threadIdx.x;     // 65536 slots
  int l = s & 63;
  int frag = s >> 6;
  int mf = frag & 31, kt = frag >> 5;
  int n = mf * 16 + (l & 15);
  int kbase = kt * 32 + (l >> 4) * 8;
  unsigned short v[8];
#pragma unroll
  for (int e = 0; e < 8; ++e) v[e] = f2bf(Wd2[(size_t)(kbase + e) * NF + n]);
  unsigned u0 = (unsigned)v[0] | ((unsigned)v[1] << 16);
  unsigned u1 = (unsigned)v[2] | ((unsigned)v[3] << 16);
  unsigned u2 = (unsigned)v[4] | ((unsigned)v[5] << 16);
  unsigned u3 = (unsigned)v[6] | ((unsigned)v[7] << 16);
  *(uint4*)(at + (size_t)s * 8) = make_uint4(u0, u1, u2, u3);
}

// hd B-fragment staging: 8 tanh -> one ds_write_b128 in frag order
__device__ __forceinline__ void stage_hd(int kt, unsigned short* dst, int q,
                                         float y0t, float y1t,
                                         const float* __restrict__ Wd1,
                                         const float* __restrict__ bd1) {
  int k = kt * 32 + q * 8;
  float4 w0a = *(const float4*)&Wd1[k];
  float4 w0b = *(const float4*)&Wd1[k + 4];
  float4 w1a = *(const float4*)&Wd1[HIDZ + k];
  float4 w1b = *(const float4*)&Wd1[HIDZ + k + 4];
  float4 ba  = *(const float4*)&bd1[k];
  float4 bb  = *(const float4*)&bd1[k + 4];
  float h[8];
  h[0] = tanhf(y0t * w0a.x + y1t * w1a.x + ba.x);
  h[1] = tanhf(y0t * w0a.y + y1t * w1a.y + ba.y);
  h[2] = tanhf(y0t * w0a.z + y1t * w1a.z + ba.z);
  h[3] = tanhf(y0t * w0a.w + y1t * w1a.w + ba.w);
  h[4] = tanhf(y0t * w0b.x + y1t * w1b.x + bb.x);
  h[5] = tanhf(y0t * w0b.y + y1t * w1b.y + bb.y);
  h[6] = tanhf(y0t * w0b.z + y1t * w1b.z + bb.z);
  h[7] = tanhf(y0t * w0b.w + y1t * w1b.w + bb.w);
  unsigned u0 = (unsigned)f2bf(h[0]) | ((unsigned)f2bf(h[1]) << 16);
  unsigned u1 = (unsigned)f2bf(h[2]) | ((unsigned)f2bf(h[3]) << 16);
  unsigned u2 = (unsigned)f2bf(h[4]) | ((unsigned)f2bf(h[5]) << 16);
  unsigned u3 = (unsigned)f2bf(h[6]) | ((unsigned)f2bf(h[7]) << 16);
  *(uint4*)dst = make_uint4(u0, u1, u2, u3);
}

// GEMM4 via MFMA 16x16x32 bf16. One block per b: BM=512(n) x 64(t), K=1024(h).
// A (Wd2T) loaded as ready-made fragments straight from global (L2-resident),
// B (hd) computed once per block into LDS in fragment order, double-buffered.
__global__ __launch_bounds__(256, 2) void k_gemm4m(const float* __restrict__ y,
                                                   const float* __restrict__ Wd1,
                                                   const float* __restrict__ bd1,
                                                   const unsigned short* __restrict__ at,
                                                   const float* __restrict__ bd2,
                                                   float* __restrict__ xae) {
  __shared__ __align__(16) unsigned short bbuf[2][4][64][8];
  __shared__ float ys[2][64];
  int b = blockIdx.x, tid = threadIdx.x;
  int w = tid >> 6, l = tid & 63;
  int c = l & 15, q = l >> 4;
  if (tid < 128) ys[tid >> 6][tid & 63] = y[((size_t)b * LATZ + (tid >> 6)) * TT + (tid & 63)];
  __syncthreads();
  int t_s = w * 16 + c;                  // wave w stages frag tf=w
  float y0t = ys[0][t_s], y1t = ys[1][t_s];
  f32x4 acc[8][4];
#pragma unroll
  for (int i = 0; i < 8; ++i)
#pragma unroll
    for (int j = 0; j < 4; ++j) acc[i][j] = (f32x4)(0.f);
  const bf16x8* A = (const bf16x8*)at;
  stage_hd(0, &bbuf[0][w][l][0], q, y0t, y1t, Wd1, bd1);
  for (int kt = 0; kt < 32; ++kt) {
    __syncthreads();
    if (kt + 1 < 32) stage_hd(kt + 1, &bbuf[(kt + 1) & 1][w][l][0], q, y0t, y1t, Wd1, bd1);
    bf16x8 bf[4];
#pragma unroll
    for (int t2 = 0; t2 < 4; ++t2) bf[t2] = *(const bf16x8*)&bbuf[kt & 1][t2][l][0];
    bf16x8 af[8];
#pragma unroll
    for (int mf = 0; mf < 8; ++mf) af[mf] = A[(size_t)((kt * 32 + w * 8 + mf) * 64) + l];
#pragma unroll
    for (int mf = 0; mf < 8; ++mf)
#pragma unroll
      for (int t2 = 0; t2 < 4; ++t2)
        acc[mf][t2] = __builtin_amdgcn_mfma_f32_16x16x32_bf16(af[mf], bf[t2], acc[mf][t2], 0, 0, 0);
  }
  // epilogue: D row = (l>>4)*4 + r (n-dim), col = l&15 (t-dim)
#pragma unroll
  for (int mf = 0; mf < 8; ++mf) {
    int nb = w * 128 + mf * 16 + q * 4;
#pragma unroll
    for (int r = 0; r < 4; ++r) {
      int n = nb + r;
      float bias = bd2[n];
#pragma unroll
      for (int t2 = 0; t2 < 4; ++t2)
        xae[((size_t)b * NF + n) * TT + t2 * 16 + c] = acc[mf][t2][r] + bias;
    }
  }
}

// G = Y-^T Y-  (63x63)
__global__ __launch_bounds__(1024) void k_G(const float* __restrict__ y, float* __restrict__ G) {
  __shared__ float ys[16][64];
  int tid = threadIdx.x;
  float acc[4] = {};
  for (int r0 = 0; r0 < 1024; r0 += 16) {
    __syncthreads();
    { int rr = tid >> 6, cc = tid & 63; ys[rr][cc] = y[(size_t)(r0 + rr) * 64 + cc]; }
    __syncthreads();
#pragma unroll
    for (int p = 0; p < 4; ++p) {
      int pair = tid + p * 1024;
      if (pair < 3969) {
        int i = pair / 63, j = pair % 63;
        float s = 0.f;
#pragma unroll
        for (int rr = 0; rr < 16; ++rr) s += ys[rr][i] * ys[rr][j];
        acc[p] += s;
      }
    }
  }
#pragma unroll
  for (int p = 0; p < 4; ++p) {
    int pair = tid + p * 1024;
    if (pair < 3969) G[pair] = acc[p];
  }
}

// Gauss-Jordan inverse of SPD 63x63 in f64
__global__ __launch_bounds__(256) void k_inv(const float* __restrict__ G, float* __restrict__ Ginv) {
  __shared__ double A[63][126];
  __shared__ double colk[63];
  int tid = threadIdx.x;
  for (int f = tid; f < 63 * 126; f += 256) {
    int i = f / 126, j = f % 126;
    A[i][j] = (j < 63) ? (double)G[i * 63 + j] : ((j - 63 == i) ? 1.0 : 0.0);
  }
  __syncthreads();
  for (int k = 0; k < 63; ++k) {
    double piv = A[k][k];
    if (tid < 63) colk[tid] = A[tid][k];
    __syncthreads();
    double rp = 1.0 / piv;
    for (int j = tid; j < 126; j += 256) A[k][j] *= rp;
    __syncthreads();
    for (int f = tid; f < 63 * 126; f += 256) {
      int i = f / 126, j = f % 126;
      if (i != k) A[i][j] -= colk[i] * A[k][j];
    }
    __syncthreads();
  }
  for (int f = tid; f < 63 * 63; f += 256) {
    int i = f / 63, j = f % 63;
    Ginv[f] = (float)A[i][63 + j];
  }
}

// P = Ginv * Y-^T  (63 x 1024)
__global__ __launch_bounds__(256) void k_P(const float* __restrict__ y,
                                           const float* __restrict__ Ginv,
                                           float* __restrict__ P) {
  __shared__ float ys[64][65];
  int r0 = blockIdx.x * 64, tid = threadIdx.x;
#pragma unroll
  for (int p = 0; p < 16; ++p) {
    int f = tid + p * 256;
    ys[f >> 6][f & 63] = y[(size_t)(r0 + (f >> 6)) * 64 + (f & 63)];
  }
  __syncthreads();
#pragma unroll
  for (int p = 0; p < 16; ++p) {
    int o = tid + p * 256;
    if (o < 4032) {
      int i = o >> 6, rr = o & 63;
      float s = 0.f;
#pragma unroll
      for (int j = 0; j < 63; ++j) s += Ginv[i * 63 + j] * ys[rr][j];
      P[(size_t)i * 1024 + r0 + rr] = s;
    }
  }
}

// proj = I - P @ Y-
__global__ __launch_bounds__(1024) void k_proj(const float* __restrict__ y,
                                               const float* __restrict__ P,
                                               float* __restrict__ proj) {
  __shared__ float ys[16][64];
  __shared__ float ps[63][16];
  int tid = threadIdx.x;
  float acc[4] = {};
  for (int r0 = 0; r0 < 1024; r0 += 16) {
    __syncthreads();
    { int rr = tid >> 6, cc = tid & 63; ys[rr][cc] = y[(size_t)(r0 + rr) * 64 + cc]; }
    if (tid < 1008) { int i = tid >> 4, rr = tid & 15; ps[i][rr] = P[(size_t)i * 1024 + r0 + rr]; }
    __syncthreads();
#pragma unroll
    for (int p = 0; p < 4; ++p) {
      int pair = tid + p * 1024;
      if (pair < 3969) {
        int i = pair / 63, j = pair % 63;
        float s = 0.f;
#pragma unroll
        for (int rr = 0; rr < 16; ++rr) s += ps[i][rr] * ys[rr][j];
        acc[p] += s;
      }
    }
  }
#pragma unroll
  for (int p = 0; p < 4; ++p) {
    int pair = tid + p * 1024;
    if (pair < 3969) {
      int i = pair / 63, j = pair % 63;
      proj[pair] = ((i == j) ? 1.f : 0.f) - acc[p];
    }
  }
}

// Amat = Y+ @ P
__global__ __launch_bounds__(256) void k_Amat(const float* __restrict__ y,
                                              const float* __restrict__ P,
                                              float* __restrict__ amat_out,
                                              float* __restrict__ a_ws) {
  __shared__ float Yp[64][65];
  __shared__ float Ps[63][64];
  int r0 = blockIdx.x * 64, p0 = blockIdx.y * 64;
  int tid = threadIdx.x, tx = tid & 15, ty = tid >> 4;
#pragma unroll
  for (int p = 0; p < 16; ++p) {
    int f = tid + p * 256;
    Yp[f >> 6][f & 63] = y[(size_t)(p0 + (f >> 6)) * 64 + (f & 63)];
  }
#pragma unroll
  for (int p = 0; p < 16; ++p) {
    int f = tid + p * 256;
    if (f < 4032) {
      int j = f >> 6, rr = f & 63;
      Ps[j][rr] = P[(size_t)j * 1024 + r0 + rr];
    }
  }
  __syncthreads();
  float acc[4][4] = {};
  for (int j = 0; j < 63; ++j) {
    float a0 = Yp[ty * 4 + 0][j + 1];
    float a1 = Yp[ty * 4 + 1][j + 1];
    float a2 = Yp[ty * 4 + 2][j + 1];
    float a3 = Yp[ty * 4 + 3][j + 1];
    float4 bv = *(float4*)&Ps[j][tx * 4];
    acc[0][0] += a0 * bv.x; acc[0][1] += a0 * bv.y; acc[0][2] += a0 * bv.z; acc[0][3] += a0 * bv.w;
    acc[1][0] += a1 * bv.x; acc[1][1] += a1 * bv.y; acc[1][2] += a1 * bv.z; acc[1][3] += a1 * bv.w;
    acc[2][0] += a2 * bv.x; acc[2][1] += a2 * bv.y; acc[2][2] += a2 * bv.z; acc[2][3] += a2 * bv.w;
    acc[3][0] += a3 * bv.x; acc[3][1] += a3 * bv.y; acc[3][2] += a3 * bv.z; acc[3][3] += a3 * bv.w;
  }
#pragma unroll
  for (int i = 0; i < 4; ++i) {
#pragma unroll
    for (int jj = 0; jj < 4; ++jj) {
      size_t idx = (size_t)(p0 + ty * 4 + i) * 1024 + r0 + tx * 4 + jj;
      amat_out[idx] = acc[i][jj];
      a_ws[idx] = acc[i][jj];
    }
  }
}

// dmd_loss = sum((Y+ @ proj)^2)
__global__ __launch_bounds__(256) void k_dmdloss(const float* __restrict__ y,
                                                 const float* __restrict__ proj,
                                                 float* __restrict__ out_dmd) {
  __shared__ float ps[3969];
  int tid = threadIdx.x;
  for (int f = tid; f < 3969; f += 256) ps[f] = proj[f];
  __syncthreads();
  int p = blockIdx.x * 256 + tid;
  float yp[63];
#pragma unroll
  for (int k = 0; k < 63; ++k) yp[k] = y[(size_t)p * 64 + k + 1];
  float accv = 0.f;
  for (int j = 0; j < 63; ++j) {
    float s = 0.f;
#pragma unroll
    for (int k = 0; k < 63; ++k) s += yp[k] * ps[k * 63 + j];
    accv += s * s;
  }
  float tot = blockReduceSum(accv);
  if (tid == 0) atomicAdd(out_dmd, tot);
}

__global__ void k_y0(const float* __restrict__ y, float* __restrict__ v0) {
  int r = threadIdx.x + blockIdx.x * 1024;
  v0[r] = y[(size_t)r * 64];
}

__global__ __launch_bounds__(256) void k_matvec(const float* __restrict__ A,
                                                const float* __restrict__ v,
                                                float* __restrict__ vout,
                                                float* __restrict__ ypred, int t) {
  int tid = threadIdx.x;
  int ry = tid >> 4, cx = tid & 15;
  int r = blockIdx.x * 16 + ry;
  const float* Ar = A + (size_t)r * 1024;
  float s = 0.f;
  for (int c0 = cx * 4; c0 < 1024; c0 += 64) {
    float4 a = *(const float4*)&Ar[c0];
    float4 vv = *(const float4*)&v[c0];
    s += a.x * vv.x + a.y * vv.y + a.z * vv.z + a.w * vv.w;
  }
#pragma unroll
  for (int off = 8; off > 0; off >>= 1) s += __shfl_down(s, off, 16);
  if (cx == 0) {
    vout[r] = s;
    ypred[(size_t)r * 64 + t] = s;
  }
}

__global__ __launch_bounds__(256) void k_predloss(const float* __restrict__ y,
                                                  const float* __restrict__ ypred,
                                                  float* __restrict__ outp) {
  int i = blockIdx.x * 256 + threadIdx.x;
  float d = ypred[i] - y[i];
  float tot = blockReduceSum(d * d);
  if (threadIdx.x == 0) atomicAdd(outp, tot * (1.f / 65536.f));
}

__global__ __launch_bounds__(256) void k_aeloss(const float* __restrict__ x,
                                                const float* __restrict__ xae,
                                                float* __restrict__ outp) {
  int i = blockIdx.x * 256 + threadIdx.x;
  float d = x[(size_t)i * 64] - xae[(size_t)i * 64];
  float tot = blockReduceSum(d * d);
  if (threadIdx.x == 0) atomicAdd(outp, tot * (1.f / 262144.f));
}

extern "C" void kernel_launch(void* const* d_in, const int* in_sizes, int n_in,
                              void* d_out, int out_size, void* d_ws, size_t ws_size,
                              hipStream_t stream) {
  (void)in_sizes; (void)n_in; (void)out_size; (void)ws_size;
  const float* x   = (const float*)d_in[0];
  const float* We1 = (const float*)d_in[1];
  const float* be1 = (const float*)d_in[2];
  const float* We2 = (const float*)d_in[3];
  const float* be2 = (const float*)d_in[4];
  const float* Wd1 = (const float*)d_in[5];
  const float* bd1 = (const float*)d_in[6];
  const float* Wd2 = (const float*)d_in[7];
  const float* bd2 = (const float*)d_in[8];
  float* out = (float*)d_out;
  float* wsf = (float*)d_ws;

  float* y_out = out + OFF_Y;
  unsigned short* wd2t = (unsigned short*)(wsf + WS_WD2T);

  k_init<<<1, 64, 0, stream>>>(out + OFF_DMD, out + OFF_AE, out + OFF_PRED);
  k_wd2t<<<256, 256, 0, stream>>>(Wd2, wd2t);
  k_gemm1<<<dim3(8, 256), 256, 0, stream>>>(x, We1, be1, We2, wsf + WS_YP);
  k_yred<<<256, 256, 0, stream>>>(wsf + WS_YP, be2, y_out);
  k_gemm4m<<<512, 256, 0, stream>>>(y_out, Wd1, bd1, wd2t, bd2, out + OFF_XAE);
  k_G<<<1, 1024, 0, stream>>>(y_out, wsf + WS_G);
  k_inv<<<1, 256, 0, stream>>>(wsf + WS_G, wsf + WS_GINV);
  k_P<<<16, 256, 0, stream>>>(y_out, wsf + WS_GINV, wsf + WS_P);
  k_proj<<<1, 1024, 0, stream>>>(y_out, wsf + WS_P, wsf + WS_PROJ);
  k_Amat<<<dim3(16, 16), 256, 0, stream>>>(y_out, wsf + WS_P, out + OFF_AMAT, wsf + WS_AM);
  k_dmdloss<<<4, 256, 0, stream>>>(y_out, wsf + WS_PROJ, out + OFF_DMD);
  k_y0<<<1, 1024, 0, stream>>>(y_out, wsf + WS_V0);
  for (int t = 0; t < 64; ++t) {
    const float* vin = wsf + ((t & 1) ? WS_V1 : WS_V0);
    float* vout = wsf + ((t & 1) ? WS_V0 : WS_V1);
    k_matvec<<<64, 256, 0, stream>>>(wsf + WS_AM, vin, vout, out + OFF_YPRED, t);
  }
  k_predloss<<<256, 256, 0, stream>>>(y_out, out + OFF_YPRED, out + OFF_PRED);
  k_aeloss<<<1024, 256, 0, stream>>>(x, out + OFF_XAE, out + OFF_AE);
}

// Round 3
// 1214.806 us; speedup vs baseline: 1.9480x; 1.4122x over previous
//
#include <hip/hip_runtime.h>
#include <hip/hip_bf16.h>

#define Bz 512
#define NF 512
#define TT 64
#define HIDZ 1024
#define LATZ 2

// output layout (floats)
static const size_t OFF_XAE   = 0;                                  // 512*512*64
static const size_t OFF_Y     = (size_t)Bz * NF * TT;               // 16777216
static const size_t OFF_DMD   = OFF_Y + (size_t)Bz * LATZ * TT;     // 16842752
static const size_t OFF_AE    = OFF_DMD + 1;                        // 16842753
static const size_t OFF_YPRED = OFF_AE + 1;                         // 16842754
static const size_t OFF_AMAT  = OFF_YPRED + (size_t)Bz * LATZ * TT; // 16908290
static const size_t OFF_PRED  = OFF_AMAT + (size_t)1024 * 1024;     // 17956866

// workspace layout (float offsets)
#define WS_G     0
#define WS_GINV  4096
#define WS_PROJ  8192
#define WS_P     16384     // 63*1024 -> ends 80896
#define WS_V0    81920     // 1024
#define WS_V1    83968     // 1024
#define WS_M0    86016     // 1024*8 -> ends 94208
#define WS_M1    94208     // 1024*8 -> ends 102400
#define WS_AM    131072    // 1024*1024 aligned copy of Amat -> ends 1179648
#define WS_YP    1179648   // 4*512*2*64 y partials -> ends 1441792
#define WS_PW0   1441792   // 1024*1024 (A2 / A8) -> ends 2490368
#define WS_PW1   2490368   // 1024*1024 (A4)      -> ends 3538944
#define WS_WD2T  3538944   // 1 MB ushort: Wd2 bf16 A-frag layout -> ends 3801088
#define WS_WE1H  3801088   // 1 MB ushort: We1 hi A-frags -> ends 4063232
#define WS_WE1L  4063232   // 1 MB ushort: We1 lo A-frags -> ends 4325376

typedef __attribute__((ext_vector_type(8))) short bf16x8;
typedef __attribute__((ext_vector_type(4))) float f32x4;

__device__ __forceinline__ unsigned short f2bf(float f) {
  unsigned u = __float_as_uint(f);
  unsigned r = (u + 0x7fffu + ((u >> 16) & 1u)) >> 16;
  return (unsigned short)r;
}
__device__ __forceinline__ float bf2f(unsigned short h) {
  return __uint_as_float((unsigned)h << 16);
}
__device__ __forceinline__ uint4 pack8(const unsigned short* v) {
  return make_uint4((unsigned)v[0] | ((unsigned)v[1] << 16),
                    (unsigned)v[2] | ((unsigned)v[3] << 16),
                    (unsigned)v[4] | ((unsigned)v[5] << 16),
                    (unsigned)v[6] | ((unsigned)v[7] << 16));
}
// split 8 f32 into hi/lo bf16x8 (in registers)
__device__ __forceinline__ void split8(const float* v, bf16x8& hi, bf16x8& lo) {
#pragma unroll
  for (int e = 0; e < 8; ++e) {
    unsigned short h = f2bf(v[e]);
    hi[e] = (short)h;
    lo[e] = (short)f2bf(v[e] - bf2f(h));
  }
}

__device__ inline float blockReduceSum(float v) {
  __shared__ float sh[16];
  int lane = threadIdx.x & 63;
  int wid  = threadIdx.x >> 6;
#pragma unroll
  for (int off = 32; off > 0; off >>= 1) v += __shfl_down(v, off, 64);
  if (lane == 0) sh[wid] = v;
  __syncthreads();
  int nw = blockDim.x >> 6;
  v = (threadIdx.x < (unsigned)nw) ? sh[threadIdx.x] : 0.f;
  if (wid == 0) {
#pragma unroll
    for (int off = 8; off > 0; off >>= 1) v += __shfl_down(v, off, 64);
  }
  return v;
}

__global__ void k_init(float* dmd, float* ae, float* pred) {
  if (threadIdx.x == 0) { *dmd = 0.f; *ae = 0.f; *pred = 0.f; }
}

// We1 [k=512][m=1024] -> A-frag hi/lo: slot s=(kt*64+mfg)*64+l, elem e:
// A[m=mfg*16+(l&15)][k=kt*32+(l>>4)*8+e]
__global__ void k_we1t(const float* __restrict__ We1,
                       unsigned short* __restrict__ ah, unsigned short* __restrict__ al) {
  int s = blockIdx.x * 256 + threadIdx.x;   // 65536 slots
  int l = s & 63, mfg = (s >> 6) & 63, kt = s >> 12;
  int m = mfg * 16 + (l & 15);
  int k0 = kt * 32 + (l >> 4) * 8;
  unsigned short h[8], lo[8];
#pragma unroll
  for (int e = 0; e < 8; ++e) {
    float v = We1[(size_t)(k0 + e) * HIDZ + m];
    h[e] = f2bf(v);
    lo[e] = f2bf(v - bf2f(h[e]));
  }
  *(uint4*)(ah + (size_t)s * 8) = pack8(h);
  *(uint4*)(al + (size_t)s * 8) = pack8(lo);
}

// GEMM1 via split-bf16 3-pass MFMA. Block: 256h x 64t for one b.
// Grid 2048 (XCD-swizzled): lbid = (o&7)*256 + (o>>3); b=lbid>>2, hb=lbid&3.
__global__ __launch_bounds__(256, 2) void k_gemm1m(const float* __restrict__ x,
    const unsigned short* __restrict__ we1h, const unsigned short* __restrict__ we1l,
    const float* __restrict__ be1, const float* __restrict__ We2,
    float* __restrict__ ypartial) {
  __shared__ uint4 bh4[4][64], bl4[4][64];
  __shared__ float yredl[4][2][64];
  int o = blockIdx.x;
  int lbid = (o & 7) * 256 + (o >> 3);
  int b = lbid >> 2, hb = lbid & 3;
  int tid = threadIdx.x, w = tid >> 6, l = tid & 63, q = l >> 4, c = l & 15;
  const float* xb = x + (size_t)b * NF * TT;
  f32x4 acc[4][4];
#pragma unroll
  for (int i = 0; i < 4; ++i)
#pragma unroll
    for (int j = 0; j < 4; ++j) acc[i][j] = (f32x4)(0.f);
  for (int kt = 0; kt < 16; ++kt) {
    // stage B frags: thread (w,l) -> slot (nf=w, l). t = w*16+c, k = kt*32+q*8+e
    {
      const float* xp = xb + (size_t)(kt * 32 + q * 8) * TT + (w * 16 + c);
      float v[8];
#pragma unroll
      for (int e = 0; e < 8; ++e) v[e] = xp[e * TT];
      unsigned short h[8], lo[8];
#pragma unroll
      for (int e = 0; e < 8; ++e) {
        h[e] = f2bf(v[e]);
        lo[e] = f2bf(v[e] - bf2f(h[e]));
      }
      bh4[w][l] = pack8(h);
      bl4[w][l] = pack8(lo);
    }
    __syncthreads();
    bf16x8 ah[4], al[4], bhf[4], blf[4];
#pragma unroll
    for (int mf = 0; mf < 4; ++mf) {
      size_t slot = ((size_t)kt * 64 + hb * 16 + w * 4 + mf) * 64 + l;
      ah[mf] = *(const bf16x8*)(we1h + slot * 8);
      al[mf] = *(const bf16x8*)(we1l + slot * 8);
    }
#pragma unroll
    for (int nf = 0; nf < 4; ++nf) {
      bhf[nf] = *(bf16x8*)&bh4[nf][l];
      blf[nf] = *(bf16x8*)&bl4[nf][l];
    }
#pragma unroll
    for (int mf = 0; mf < 4; ++mf)
#pragma unroll
      for (int nf = 0; nf < 4; ++nf) {
        acc[mf][nf] = __builtin_amdgcn_mfma_f32_16x16x32_bf16(ah[mf], bhf[nf], acc[mf][nf], 0, 0, 0);
        acc[mf][nf] = __builtin_amdgcn_mfma_f32_16x16x32_bf16(ah[mf], blf[nf], acc[mf][nf], 0, 0, 0);
        acc[mf][nf] = __builtin_amdgcn_mfma_f32_16x16x32_bf16(al[mf], bhf[nf], acc[mf][nf], 0, 0, 0);
      }
    __syncthreads();
  }
  // epilogue: tanh + We2 reduce (deterministic)
  float p0[4] = {0.f, 0.f, 0.f, 0.f}, p1[4] = {0.f, 0.f, 0.f, 0.f};
#pragma unroll
  for (int mf = 0; mf < 4; ++mf) {
    int hbase = hb * 256 + w * 64 + mf * 16 + q * 4;
#pragma unroll
    for (int r = 0; r < 4; ++r) {
      int hh = hbase + r;
      float bias = be1[hh];
      float w20 = We2[2 * hh], w21 = We2[2 * hh + 1];
#pragma unroll
      for (int nf = 0; nf < 4; ++nf) {
        float hv = tanhf(acc[mf][nf][r] + bias);
        p0[nf] += hv * w20;
        p1[nf] += hv * w21;
      }
    }
  }
#pragma unroll
  for (int nf = 0; nf < 4; ++nf) {
    p0[nf] += __shfl_xor(p0[nf], 16, 64); p0[nf] += __shfl_xor(p0[nf], 32, 64);
    p1[nf] += __shfl_xor(p1[nf], 16, 64); p1[nf] += __shfl_xor(p1[nf], 32, 64);
  }
  if (q == 0) {
#pragma unroll
    for (int nf = 0; nf < 4; ++nf) {
      yredl[w][0][nf * 16 + c] = p0[nf];
      yredl[w][1][nf * 16 + c] = p1[nf];
    }
  }
  __syncthreads();
  if (tid < 128) {
    int lat = tid >> 6, t = tid & 63;
    float s = yredl[0][lat][t] + yredl[1][lat][t] + yredl[2][lat][t] + yredl[3][lat][t];
    ypartial[(((size_t)hb * Bz + b) * LATZ + lat) * TT + t] = s;
  }
}

// y = be2 + sum of 4 h-block partials (fixed order)
__global__ void k_yred(const float* __restrict__ yp, const float* __restrict__ be2,
                       float* __restrict__ y) {
  int idx = blockIdx.x * 256 + threadIdx.x;   // 65536
  int t = idx & 63, l = (idx >> 6) & 1, b = idx >> 7;
  float s = be2[l];
#pragma unroll
  for (int hb = 0; hb < 4; ++hb) s += yp[(((size_t)hb * Bz + b) * LATZ + l) * TT + t];
  y[idx] = s;
}

// Wd2 (f32 [k=1024][n=512]) -> bf16 MFMA A-fragment layout
__global__ void k_wd2t(const float* __restrict__ Wd2, unsigned short* __restrict__ at) {
  int s = blockIdx.x * 256 + threadIdx.x;     // 65536 slots
  int l = s & 63;
  int frag = s >> 6;
  int mf = frag & 31, kt = frag >> 5;
  int n = mf * 16 + (l & 15);
  int kbase = kt * 32 + (l >> 4) * 8;
  unsigned short v[8];
#pragma unroll
  for (int e = 0; e < 8; ++e) v[e] = f2bf(Wd2[(size_t)(kbase + e) * NF + n]);
  *(uint4*)(at + (size_t)s * 8) = pack8(v);
}

// hd B-fragment staging: 8 tanh -> one ds_write_b128 in frag order
__device__ __forceinline__ void stage_hd(int kt, unsigned short* dst, int q,
                                         float y0t, float y1t,
                                         const float* __restrict__ Wd1,
                                         const float* __restrict__ bd1) {
  int k = kt * 32 + q * 8;
  float4 w0a = *(const float4*)&Wd1[k];
  float4 w0b = *(const float4*)&Wd1[k + 4];
  float4 w1a = *(const float4*)&Wd1[HIDZ + k];
  float4 w1b = *(const float4*)&Wd1[HIDZ + k + 4];
  float4 ba  = *(const float4*)&bd1[k];
  float4 bb  = *(const float4*)&bd1[k + 4];
  float h[8];
  h[0] = tanhf(y0t * w0a.x + y1t * w1a.x + ba.x);
  h[1] = tanhf(y0t * w0a.y + y1t * w1a.y + ba.y);
  h[2] = tanhf(y0t * w0a.z + y1t * w1a.z + ba.z);
  h[3] = tanhf(y0t * w0a.w + y1t * w1a.w + ba.w);
  h[4] = tanhf(y0t * w0b.x + y1t * w1b.x + bb.x);
  h[5] = tanhf(y0t * w0b.y + y1t * w1b.y + bb.y);
  h[6] = tanhf(y0t * w0b.z + y1t * w1b.z + bb.z);
  h[7] = tanhf(y0t * w0b.w + y1t * w1b.w + bb.w);
  unsigned short hv[8];
#pragma unroll
  for (int e = 0; e < 8; ++e) hv[e] = f2bf(h[e]);
  *(uint4*)dst = pack8(hv);
}

// GEMM4 via MFMA 16x16x32 bf16 (verified layout). One block per b.
__global__ __launch_bounds__(256, 2) void k_gemm4m(const float* __restrict__ y,
                                                   const float* __restrict__ Wd1,
                                                   const float* __restrict__ bd1,
                                                   const unsigned short* __restrict__ at,
                                                   const float* __restrict__ bd2,
                                                   float* __restrict__ xae) {
  __shared__ __align__(16) unsigned short bbuf[2][4][64][8];
  __shared__ float ys[2][64];
  int b = blockIdx.x, tid = threadIdx.x;
  int w = tid >> 6, l = tid & 63;
  int c = l & 15, q = l >> 4;
  if (tid < 128) ys[tid >> 6][tid & 63] = y[((size_t)b * LATZ + (tid >> 6)) * TT + (tid & 63)];
  __syncthreads();
  int t_s = w * 16 + c;
  float y0t = ys[0][t_s], y1t = ys[1][t_s];
  f32x4 acc[8][4];
#pragma unroll
  for (int i = 0; i < 8; ++i)
#pragma unroll
    for (int j = 0; j < 4; ++j) acc[i][j] = (f32x4)(0.f);
  const bf16x8* A = (const bf16x8*)at;
  stage_hd(0, &bbuf[0][w][l][0], q, y0t, y1t, Wd1, bd1);
  for (int kt = 0; kt < 32; ++kt) {
    __syncthreads();
    if (kt + 1 < 32) stage_hd(kt + 1, &bbuf[(kt + 1) & 1][w][l][0], q, y0t, y1t, Wd1, bd1);
    bf16x8 bf[4];
#pragma unroll
    for (int t2 = 0; t2 < 4; ++t2) bf[t2] = *(const bf16x8*)&bbuf[kt & 1][t2][l][0];
    bf16x8 af[8];
#pragma unroll
    for (int mf = 0; mf < 8; ++mf) af[mf] = A[(size_t)((kt * 32 + w * 8 + mf) * 64) + l];
#pragma unroll
    for (int mf = 0; mf < 8; ++mf)
#pragma unroll
      for (int t2 = 0; t2 < 4; ++t2)
        acc[mf][t2] = __builtin_amdgcn_mfma_f32_16x16x32_bf16(af[mf], bf[t2], acc[mf][t2], 0, 0, 0);
  }
#pragma unroll
  for (int mf = 0; mf < 8; ++mf) {
    int nb = w * 128 + mf * 16 + q * 4;
#pragma unroll
    for (int r = 0; r < 4; ++r) {
      int n = nb + r;
      float bias = bd2[n];
#pragma unroll
      for (int t2 = 0; t2 < 4; ++t2)
        xae[((size_t)b * NF + n) * TT + t2 * 16 + c] = acc[mf][t2][r] + bias;
    }
  }
}

// G = Y-^T Y-  (63x63)
__global__ __launch_bounds__(1024) void k_G(const float* __restrict__ y, float* __restrict__ G) {
  __shared__ float ys[16][64];
  int tid = threadIdx.x;
  float acc[4] = {};
  for (int r0 = 0; r0 < 1024; r0 += 16) {
    __syncthreads();
    { int rr = tid >> 6, cc = tid & 63; ys[rr][cc] = y[(size_t)(r0 + rr) * 64 + cc]; }
    __syncthreads();
#pragma unroll
    for (int p = 0; p < 4; ++p) {
      int pair = tid + p * 1024;
      if (pair < 3969) {
        int i = pair / 63, j = pair % 63;
        float s = 0.f;
#pragma unroll
        for (int rr = 0; rr < 16; ++rr) s += ys[rr][i] * ys[rr][j];
        acc[p] += s;
      }
    }
  }
#pragma unroll
  for (int p = 0; p < 4; ++p) {
    int pair = tid + p * 1024;
    if (pair < 3969) G[pair] = acc[p];
  }
}

// Gauss-Jordan inverse of SPD 63x63 in f64
__global__ __launch_bounds__(256) void k_inv(const float* __restrict__ G, float* __restrict__ Ginv) {
  __shared__ double A[63][126];
  __shared__ double colk[63];
  int tid = threadIdx.x;
  for (int f = tid; f < 63 * 126; f += 256) {
    int i = f / 126, j = f % 126;
    A[i][j] = (j < 63) ? (double)G[i * 63 + j] : ((j - 63 == i) ? 1.0 : 0.0);
  }
  __syncthreads();
  for (int k = 0; k < 63; ++k) {
    double piv = A[k][k];
    if (tid < 63) colk[tid] = A[tid][k];
    __syncthreads();
    double rp = 1.0 / piv;
    for (int j = tid; j < 126; j += 256) A[k][j] *= rp;
    __syncthreads();
    for (int f = tid; f < 63 * 126; f += 256) {
      int i = f / 126, j = f % 126;
      if (i != k) A[i][j] -= colk[i] * A[k][j];
    }
    __syncthreads();
  }
  for (int f = tid; f < 63 * 63; f += 256) {
    int i = f / 63, j = f % 63;
    Ginv[f] = (float)A[i][63 + j];
  }
}

// P = Ginv * Y-^T  (63 x 1024)
__global__ __launch_bounds__(256) void k_P(const float* __restrict__ y,
                                           const float* __restrict__ Ginv,
                                           float* __restrict__ P) {
  __shared__ float ys[64][65];
  int r0 = blockIdx.x * 64, tid = threadIdx.x;
#pragma unroll
  for (int p = 0; p < 16; ++p) {
    int f = tid + p * 256;
    ys[f >> 6][f & 63] = y[(size_t)(r0 + (f >> 6)) * 64 + (f & 63)];
  }
  __syncthreads();
#pragma unroll
  for (int p = 0; p < 16; ++p) {
    int o = tid + p * 256;
    if (o < 4032) {
      int i = o >> 6, rr = o & 63;
      float s = 0.f;
#pragma unroll
      for (int j = 0; j < 63; ++j) s += Ginv[i * 63 + j] * ys[rr][j];
      P[(size_t)i * 1024 + r0 + rr] = s;
    }
  }
}

// proj = I - P @ Y-
__global__ __launch_bounds__(1024) void k_proj(const float* __restrict__ y,
                                               const float* __restrict__ P,
                                               float* __restrict__ proj) {
  __shared__ float ys[16][64];
  __shared__ float ps[63][16];
  int tid = threadIdx.x;
  float acc[4] = {};
  for (int r0 = 0; r0 < 1024; r0 += 16) {
    __syncthreads();
    { int rr = tid >> 6, cc = tid & 63; ys[rr][cc] = y[(size_t)(r0 + rr) * 64 + cc]; }
    if (tid < 1008) { int i = tid >> 4, rr = tid & 15; ps[i][rr] = P[(size_t)i * 1024 + r0 + rr]; }
    __syncthreads();
#pragma unroll
    for (int p = 0; p < 4; ++p) {
      int pair = tid + p * 1024;
      if (pair < 3969) {
        int i = pair / 63, j = pair % 63;
        float s = 0.f;
#pragma unroll
        for (int rr = 0; rr < 16; ++rr) s += ps[i][rr] * ys[rr][j];
        acc[p] += s;
      }
    }
  }
#pragma unroll
  for (int p = 0; p < 4; ++p) {
    int pair = tid + p * 1024;
    if (pair < 3969) {
      int i = pair / 63, j = pair % 63;
      proj[pair] = ((i == j) ? 1.f : 0.f) - acc[p];
    }
  }
}

// Amat = Y+ @ P
__global__ __launch_bounds__(256) void k_Amat(const float* __restrict__ y,
                                              const float* __restrict__ P,
                                              float* __restrict__ amat_out,
                                              float* __restrict__ a_ws) {
  __shared__ float Yp[64][65];
  __shared__ float Ps[63][64];
  int r0 = blockIdx.x * 64, p0 = blockIdx.y * 64;
  int tid = threadIdx.x, tx = tid & 15, ty = tid >> 4;
#pragma unroll
  for (int p = 0; p < 16; ++p) {
    int f = tid + p * 256;
    Yp[f >> 6][f & 63] = y[(size_t)(p0 + (f >> 6)) * 64 + (f & 63)];
  }
#pragma unroll
  for (int p = 0; p < 16; ++p) {
    int f = tid + p * 256;
    if (f < 4032) {
      int j = f >> 6, rr = f & 63;
      Ps[j][rr] = P[(size_t)j * 1024 + r0 + rr];
    }
  }
  __syncthreads();
  float acc[4][4] = {};
  for (int j = 0; j < 63; ++j) {
    float a0 = Yp[ty * 4 + 0][j + 1];
    float a1 = Yp[ty * 4 + 1][j + 1];
    float a2 = Yp[ty * 4 + 2][j + 1];
    float a3 = Yp[ty * 4 + 3][j + 1];
    float4 bv = *(float4*)&Ps[j][tx * 4];
    acc[0][0] += a0 * bv.x; acc[0][1] += a0 * bv.y; acc[0][2] += a0 * bv.z; acc[0][3] += a0 * bv.w;
    acc[1][0] += a1 * bv.x; acc[1][1] += a1 * bv.y; acc[1][2] += a1 * bv.z; acc[1][3] += a1 * bv.w;
    acc[2][0] += a2 * bv.x; acc[2][1] += a2 * bv.y; acc[2][2] += a2 * bv.z; acc[2][3] += a2 * bv.w;
    acc[3][0] += a3 * bv.x; acc[3][1] += a3 * bv.y; acc[3][2] += a3 * bv.z; acc[3][3] += a3 * bv.w;
  }
#pragma unroll
  for (int i = 0; i < 4; ++i) {
#pragma unroll
    for (int jj = 0; jj < 4; ++jj) {
      size_t idx = (size_t)(p0 + ty * 4 + i) * 1024 + r0 + tx * 4 + jj;
      amat_out[idx] = acc[i][jj];
      a_ws[idx] = acc[i][jj];
    }
  }
}

// dmd_loss = sum((Y+ @ proj)^2)
__global__ __launch_bounds__(256) void k_dmdloss(const float* __restrict__ y,
                                                 const float* __restrict__ proj,
                                                 float* __restrict__ out_dmd) {
  __shared__ float ps[3969];
  int tid = threadIdx.x;
  for (int f = tid; f < 3969; f += 256) ps[f] = proj[f];
  __syncthreads();
  int p = blockIdx.x * 256 + tid;
  float yp[63];
#pragma unroll
  for (int k = 0; k < 63; ++k) yp[k] = y[(size_t)p * 64 + k + 1];
  float accv = 0.f;
  for (int j = 0; j < 63; ++j) {
    float s = 0.f;
#pragma unroll
    for (int k = 0; k < 63; ++k) s += yp[k] * ps[k * 63 + j];
    accv += s * s;
  }
  float tot = blockReduceSum(accv);
  if (tid == 0) atomicAdd(out_dmd, tot);
}

__global__ void k_y0(const float* __restrict__ y, float* __restrict__ v0) {
  int r = threadIdx.x + blockIdx.x * 1024;
  v0[r] = y[(size_t)r * 64];
}

// vout = A @ v; ypred[:, t] = vout; also M0[:, t] = vout (t<8)
__global__ __launch_bounds__(256) void k_matvec(const float* __restrict__ A,
                                                const float* __restrict__ v,
                                                float* __restrict__ vout,
                                                float* __restrict__ ypred,
                                                float* __restrict__ mcol, int t) {
  int tid = threadIdx.x;
  int ry = tid >> 4, cx = tid & 15;
  int r = blockIdx.x * 16 + ry;
  const float* Ar = A + (size_t)r * 1024;
  float s = 0.f;
  for (int c0 = cx * 4; c0 < 1024; c0 += 64) {
    float4 a = *(const float4*)&Ar[c0];
    float4 vv = *(const float4*)&v[c0];
    s += a.x * vv.x + a.y * vv.y + a.z * vv.z + a.w * vv.w;
  }
#pragma unroll
  for (int off = 8; off > 0; off >>= 1) s += __shfl_down(s, off, 16);
  if (cx == 0) {
    vout[r] = s;
    ypred[(size_t)r * 64 + t] = s;
    mcol[(size_t)r * 8 + t] = s;
  }
}

// C = X @ X (1024x1024) via split-bf16 3-pass MFMA, f32 in/out (operands L2-resident)
__global__ __launch_bounds__(256) void k_sq(const float* __restrict__ X, float* __restrict__ C) {
  int bm = blockIdx.y, bn = blockIdx.x;
  int tid = threadIdx.x, w = tid >> 6, l = tid & 63, q = l >> 4, c = l & 15;
  int mb = bm * 64 + (w >> 1) * 32, nb = bn * 64 + (w & 1) * 32;
  f32x4 acc[2][2];
#pragma unroll
  for (int i = 0; i < 2; ++i)
#pragma unroll
    for (int j = 0; j < 2; ++j) acc[i][j] = (f32x4)(0.f);
  for (int kt = 0; kt < 32; ++kt) {
    bf16x8 ah[2], al[2], bh[2], bl[2];
#pragma unroll
    for (int mf = 0; mf < 2; ++mf) {
      const float* xp = X + (size_t)(mb + mf * 16 + c) * 1024 + kt * 32 + q * 8;
      float v[8];
      *(float4*)&v[0] = *(const float4*)xp;
      *(float4*)&v[4] = *(const float4*)(xp + 4);
      split8(v, ah[mf], al[mf]);
    }
#pragma unroll
    for (int nf = 0; nf < 2; ++nf) {
      const float* xp = X + (size_t)(kt * 32 + q * 8) * 1024 + nb + nf * 16 + c;
      float v[8];
#pragma unroll
      for (int e = 0; e < 8; ++e) v[e] = xp[e * 1024];
      split8(v, bh[nf], bl[nf]);
    }
#pragma unroll
    for (int mf = 0; mf < 2; ++mf)
#pragma unroll
      for (int nf = 0; nf < 2; ++nf) {
        acc[mf][nf] = __builtin_amdgcn_mfma_f32_16x16x32_bf16(ah[mf], bh[nf], acc[mf][nf], 0, 0, 0);
        acc[mf][nf] = __builtin_amdgcn_mfma_f32_16x16x32_bf16(ah[mf], bl[nf], acc[mf][nf], 0, 0, 0);
        acc[mf][nf] = __builtin_amdgcn_mfma_f32_16x16x32_bf16(al[mf], bh[nf], acc[mf][nf], 0, 0, 0);
      }
  }
#pragma unroll
  for (int mf = 0; mf < 2; ++mf)
#pragma unroll
    for (int nf = 0; nf < 2; ++nf)
#pragma unroll
      for (int r = 0; r < 4; ++r)
        C[(size_t)(mb + mf * 16 + q * 4 + r) * 1024 + nb + nf * 16 + c] = acc[mf][nf][r];
}

// Mout = A8 @ Min (1024x8); ypred[:, tbase+j] = Mout[:, j]
__global__ __launch_bounds__(256) void k_bstep(const float* __restrict__ A8,
                                               const float* __restrict__ Min,
                                               float* __restrict__ Mout,
                                               float* __restrict__ ypred, int tbase) {
  __shared__ float m0[8][1024];
  int tid = threadIdx.x;
  for (int i = tid; i < 8192; i += 256) m0[i & 7][i >> 3] = Min[i];
  __syncthreads();
  int ry = tid >> 4, cx = tid & 15;
  int r = blockIdx.x * 16 + ry;
  const float* Ar = A8 + (size_t)r * 1024;
  float acc8[8] = {};
  for (int k0 = cx * 4; k0 < 1024; k0 += 64) {
    float4 a = *(const float4*)&Ar[k0];
#pragma unroll
    for (int kk = 0; kk < 4; ++kk) {
      float av = (&a.x)[kk];
      int k = k0 + kk;
#pragma unroll
      for (int j = 0; j < 8; ++j) acc8[j] += av * m0[j][k];
    }
  }
#pragma unroll
  for (int j = 0; j < 8; ++j) {
#pragma unroll
    for (int off = 8; off > 0; off >>= 1) acc8[j] += __shfl_xor(acc8[j], off, 16);
  }
  if (cx == 0) {
#pragma unroll
    for (int j = 0; j < 8; ++j) {
      Mout[(size_t)r * 8 + j] = acc8[j];
      ypred[(size_t)r * 64 + tbase + j] = acc8[j];
    }
  }
}

__global__ __launch_bounds__(256) void k_predloss(const float* __restrict__ y,
                                                  const float* __restrict__ ypred,
                                                  float* __restrict__ outp) {
  int i = blockIdx.x * 256 + threadIdx.x;
  float d = ypred[i] - y[i];
  float tot = blockReduceSum(d * d);
  if (threadIdx.x == 0) atomicAdd(outp, tot * (1.f / 65536.f));
}

__global__ __launch_bounds__(256) void k_aeloss(const float* __restrict__ x,
                                                const float* __restrict__ xae,
                                                float* __restrict__ outp) {
  int i = blockIdx.x * 256 + threadIdx.x;
  float d = x[(size_t)i * 64] - xae[(size_t)i * 64];
  float tot = blockReduceSum(d * d);
  if (threadIdx.x == 0) atomicAdd(outp, tot * (1.f / 262144.f));
}

extern "C" void kernel_launch(void* const* d_in, const int* in_sizes, int n_in,
                              void* d_out, int out_size, void* d_ws, size_t ws_size,
                              hipStream_t stream) {
  (void)in_sizes; (void)n_in; (void)out_size; (void)ws_size;
  const float* x   = (const float*)d_in[0];
  const float* We1 = (const float*)d_in[1];
  const float* be1 = (const float*)d_in[2];
  const float* We2 = (const float*)d_in[3];
  const float* be2 = (const float*)d_in[4];
  const float* Wd1 = (const float*)d_in[5];
  const float* bd1 = (const float*)d_in[6];
  const float* Wd2 = (const float*)d_in[7];
  const float* bd2 = (const float*)d_in[8];
  float* out = (float*)d_out;
  float* wsf = (float*)d_ws;

  float* y_out = out + OFF_Y;
  unsigned short* wd2t = (unsigned short*)(wsf + WS_WD2T);
  unsigned short* we1h = (unsigned short*)(wsf + WS_WE1H);
  unsigned short* we1l = (unsigned short*)(wsf + WS_WE1L);

  k_init<<<1, 64, 0, stream>>>(out + OFF_DMD, out + OFF_AE, out + OFF_PRED);
  k_we1t<<<256, 256, 0, stream>>>(We1, we1h, we1l);
  k_wd2t<<<256, 256, 0, stream>>>(Wd2, wd2t);
  k_gemm1m<<<2048, 256, 0, stream>>>(x, we1h, we1l, be1, We2, wsf + WS_YP);
  k_yred<<<256, 256, 0, stream>>>(wsf + WS_YP, be2, y_out);
  k_gemm4m<<<512, 256, 0, stream>>>(y_out, Wd1, bd1, wd2t, bd2, out + OFF_XAE);
  k_G<<<1, 1024, 0, stream>>>(y_out, wsf + WS_G);
  k_inv<<<1, 256, 0, stream>>>(wsf + WS_G, wsf + WS_GINV);
  k_P<<<16, 256, 0, stream>>>(y_out, wsf + WS_GINV, wsf + WS_P);
  k_proj<<<1, 1024, 0, stream>>>(y_out, wsf + WS_P, wsf + WS_PROJ);
  k_Amat<<<dim3(16, 16), 256, 0, stream>>>(y_out, wsf + WS_P, out + OFF_AMAT, wsf + WS_AM);
  k_dmdloss<<<4, 256, 0, stream>>>(y_out, wsf + WS_PROJ, out + OFF_DMD);
  // A^2, A^4, A^8
  k_sq<<<dim3(16, 16), 256, 0, stream>>>(wsf + WS_AM, wsf + WS_PW0);
  k_sq<<<dim3(16, 16), 256, 0, stream>>>(wsf + WS_PW0, wsf + WS_PW1);
  k_sq<<<dim3(16, 16), 256, 0, stream>>>(wsf + WS_PW1, wsf + WS_PW0);
  k_y0<<<1, 1024, 0, stream>>>(y_out, wsf + WS_V0);
  // u_j = A^j y0 = preds[0..7]
  for (int t = 0; t < 8; ++t) {
    const float* vin = wsf + ((t & 1) ? WS_V1 : WS_V0);
    float* vout = wsf + ((t & 1) ? WS_V0 : WS_V1);
    k_matvec<<<64, 256, 0, stream>>>(wsf + WS_AM, vin, vout, out + OFF_YPRED, wsf + WS_M0, t);
  }
  // M_a = A8 @ M_{a-1} = preds[8a .. 8a+7]
  for (int a = 1; a < 8; ++a) {
    const float* min = wsf + (((a - 1) & 1) ? WS_M1 : WS_M0);
    float* mout = wsf + ((a & 1) ? WS_M1 : WS_M0);
    k_bstep<<<64, 256, 0, stream>>>(wsf + WS_PW0, min, mout, out + OFF_YPRED, 8 * a);
  }
  k_predloss<<<256, 256, 0, stream>>>(y_out, out + OFF_YPRED, out + OFF_PRED);
  k_aeloss<<<1024, 256, 0, stream>>>(x, out + OFF_XAE, out + OFF_AE);
}

// Round 4
// 1046.175 us; speedup vs baseline: 2.2620x; 1.1612x over previous
//
#include <hip/hip_runtime.h>
#include <hip/hip_bf16.h>

#define Bz 512
#define NF 512
#define TT 64
#define HIDZ 1024
#define LATZ 2

// output layout (floats)
static const size_t OFF_XAE   = 0;                                  // 512*512*64
static const size_t OFF_Y     = (size_t)Bz * NF * TT;               // 16777216
static const size_t OFF_DMD   = OFF_Y + (size_t)Bz * LATZ * TT;     // 16842752
static const size_t OFF_AE    = OFF_DMD + 1;                        // 16842753
static const size_t OFF_YPRED = OFF_AE + 1;                         // 16842754
static const size_t OFF_AMAT  = OFF_YPRED + (size_t)Bz * LATZ * TT; // 16908290
static const size_t OFF_PRED  = OFF_AMAT + (size_t)1024 * 1024;     // 17956866

// workspace layout (float offsets)
#define WS_G     0
#define WS_GINV  4096
#define WS_PROJ  8192
#define WS_P     16384     // 63*1024 -> ends 80896
#define WS_V0    81920     // 1024
#define WS_V1    83968     // 1024
#define WS_M0    86016     // 1024*8 -> ends 94208
#define WS_M1    94208     // 1024*8 -> ends 102400
#define WS_AM    131072    // 1024*1024 aligned copy of Amat -> ends 1179648
#define WS_YP    1179648   // 4*512*2*64 y partials -> ends 1441792
#define WS_PW0   1441792   // 1024*1024 (A2 / A8) -> ends 2490368
#define WS_PW1   2490368   // 1024*1024 (A4)      -> ends 3538944
#define WS_WD2T  3538944   // 1 MB ushort: Wd2 bf16 A-frag layout -> ends 3801088
#define WS_WE1H  3801088   // 1 MB ushort: We1 hi A-frags -> ends 4063232
#define WS_WE1L  4063232   // 1 MB ushort: We1 lo A-frags -> ends 4325376

typedef __attribute__((ext_vector_type(8))) short bf16x8;
typedef __attribute__((ext_vector_type(4))) float f32x4;

__device__ __forceinline__ unsigned short f2bf(float f) {
  unsigned u = __float_as_uint(f);
  unsigned r = (u + 0x7fffu + ((u >> 16) & 1u)) >> 16;
  return (unsigned short)r;
}
__device__ __forceinline__ float bf2f(unsigned short h) {
  return __uint_as_float((unsigned)h << 16);
}
__device__ __forceinline__ uint4 pack8(const unsigned short* v) {
  return make_uint4((unsigned)v[0] | ((unsigned)v[1] << 16),
                    (unsigned)v[2] | ((unsigned)v[3] << 16),
                    (unsigned)v[4] | ((unsigned)v[5] << 16),
                    (unsigned)v[6] | ((unsigned)v[7] << 16));
}
// split 8 f32 into hi/lo bf16x8 (in registers)
__device__ __forceinline__ void split8(const float* v, bf16x8& hi, bf16x8& lo) {
#pragma unroll
  for (int e = 0; e < 8; ++e) {
    unsigned short h = f2bf(v[e]);
    hi[e] = (short)h;
    lo[e] = (short)f2bf(v[e] - bf2f(h));
  }
}

__device__ inline float blockReduceSum(float v) {
  __shared__ float sh[16];
  int lane = threadIdx.x & 63;
  int wid  = threadIdx.x >> 6;
#pragma unroll
  for (int off = 32; off > 0; off >>= 1) v += __shfl_down(v, off, 64);
  if (lane == 0) sh[wid] = v;
  __syncthreads();
  int nw = blockDim.x >> 6;
  v = (threadIdx.x < (unsigned)nw) ? sh[threadIdx.x] : 0.f;
  if (wid == 0) {
#pragma unroll
    for (int off = 8; off > 0; off >>= 1) v += __shfl_down(v, off, 64);
  }
  return v;
}

__global__ void k_init(float* dmd, float* ae, float* pred) {
  if (threadIdx.x == 0) { *dmd = 0.f; *ae = 0.f; *pred = 0.f; }
}

// We1 [k=512][m=1024] -> A-frag hi/lo: slot s=(kt*64+mfg)*64+l, elem e:
// A[m=mfg*16+(l&15)][k=kt*32+(l>>4)*8+e]
__global__ void k_we1t(const float* __restrict__ We1,
                       unsigned short* __restrict__ ah, unsigned short* __restrict__ al) {
  int s = blockIdx.x * 256 + threadIdx.x;   // 65536 slots
  int l = s & 63, mfg = (s >> 6) & 63, kt = s >> 12;
  int m = mfg * 16 + (l & 15);
  int k0 = kt * 32 + (l >> 4) * 8;
  unsigned short h[8], lo[8];
#pragma unroll
  for (int e = 0; e < 8; ++e) {
    float v = We1[(size_t)(k0 + e) * HIDZ + m];
    h[e] = f2bf(v);
    lo[e] = f2bf(v - bf2f(h[e]));
  }
  *(uint4*)(ah + (size_t)s * 8) = pack8(h);
  *(uint4*)(al + (size_t)s * 8) = pack8(lo);
}

// GEMM1 via split-bf16 3-pass MFMA. Block: 256h x 64t for one b.
// Grid 2048 (XCD-swizzled): lbid = (o&7)*256 + (o>>3); b=lbid>>2, hb=lbid&3.
__global__ __launch_bounds__(256, 2) void k_gemm1m(const float* __restrict__ x,
    const unsigned short* __restrict__ we1h, const unsigned short* __restrict__ we1l,
    const float* __restrict__ be1, const float* __restrict__ We2,
    float* __restrict__ ypartial) {
  __shared__ uint4 bh4[4][64], bl4[4][64];
  __shared__ float yredl[4][2][64];
  int o = blockIdx.x;
  int lbid = (o & 7) * 256 + (o >> 3);
  int b = lbid >> 2, hb = lbid & 3;
  int tid = threadIdx.x, w = tid >> 6, l = tid & 63, q = l >> 4, c = l & 15;
  const float* xb = x + (size_t)b * NF * TT;
  f32x4 acc[4][4];
#pragma unroll
  for (int i = 0; i < 4; ++i)
#pragma unroll
    for (int j = 0; j < 4; ++j) acc[i][j] = (f32x4)(0.f);
  for (int kt = 0; kt < 16; ++kt) {
    // stage B frags: thread (w,l) -> slot (nf=w, l). t = w*16+c, k = kt*32+q*8+e
    {
      const float* xp = xb + (size_t)(kt * 32 + q * 8) * TT + (w * 16 + c);
      float v[8];
#pragma unroll
      for (int e = 0; e < 8; ++e) v[e] = xp[e * TT];
      unsigned short h[8], lo[8];
#pragma unroll
      for (int e = 0; e < 8; ++e) {
        h[e] = f2bf(v[e]);
        lo[e] = f2bf(v[e] - bf2f(h[e]));
      }
      bh4[w][l] = pack8(h);
      bl4[w][l] = pack8(lo);
    }
    __syncthreads();
    bf16x8 ah[4], al[4], bhf[4], blf[4];
#pragma unroll
    for (int mf = 0; mf < 4; ++mf) {
      size_t slot = ((size_t)kt * 64 + hb * 16 + w * 4 + mf) * 64 + l;
      ah[mf] = *(const bf16x8*)(we1h + slot * 8);
      al[mf] = *(const bf16x8*)(we1l + slot * 8);
    }
#pragma unroll
    for (int nf = 0; nf < 4; ++nf) {
      bhf[nf] = *(bf16x8*)&bh4[nf][l];
      blf[nf] = *(bf16x8*)&bl4[nf][l];
    }
#pragma unroll
    for (int mf = 0; mf < 4; ++mf)
#pragma unroll
      for (int nf = 0; nf < 4; ++nf) {
        acc[mf][nf] = __builtin_amdgcn_mfma_f32_16x16x32_bf16(ah[mf], bhf[nf], acc[mf][nf], 0, 0, 0);
        acc[mf][nf] = __builtin_amdgcn_mfma_f32_16x16x32_bf16(ah[mf], blf[nf], acc[mf][nf], 0, 0, 0);
        acc[mf][nf] = __builtin_amdgcn_mfma_f32_16x16x32_bf16(al[mf], bhf[nf], acc[mf][nf], 0, 0, 0);
      }
    __syncthreads();
  }
  // epilogue: tanh + We2 reduce (deterministic)
  float p0[4] = {0.f, 0.f, 0.f, 0.f}, p1[4] = {0.f, 0.f, 0.f, 0.f};
#pragma unroll
  for (int mf = 0; mf < 4; ++mf) {
    int hbase = hb * 256 + w * 64 + mf * 16 + q * 4;
#pragma unroll
    for (int r = 0; r < 4; ++r) {
      int hh = hbase + r;
      float bias = be1[hh];
      float w20 = We2[2 * hh], w21 = We2[2 * hh + 1];
#pragma unroll
      for (int nf = 0; nf < 4; ++nf) {
        float hv = tanhf(acc[mf][nf][r] + bias);
        p0[nf] += hv * w20;
        p1[nf] += hv * w21;
      }
    }
  }
#pragma unroll
  for (int nf = 0; nf < 4; ++nf) {
    p0[nf] += __shfl_xor(p0[nf], 16, 64); p0[nf] += __shfl_xor(p0[nf], 32, 64);
    p1[nf] += __shfl_xor(p1[nf], 16, 64); p1[nf] += __shfl_xor(p1[nf], 32, 64);
  }
  if (q == 0) {
#pragma unroll
    for (int nf = 0; nf < 4; ++nf) {
      yredl[w][0][nf * 16 + c] = p0[nf];
      yredl[w][1][nf * 16 + c] = p1[nf];
    }
  }
  __syncthreads();
  if (tid < 128) {
    int lat = tid >> 6, t = tid & 63;
    float s = yredl[0][lat][t] + yredl[1][lat][t] + yredl[2][lat][t] + yredl[3][lat][t];
    ypartial[(((size_t)hb * Bz + b) * LATZ + lat) * TT + t] = s;
  }
}

// y = be2 + sum of 4 h-block partials (fixed order)
__global__ void k_yred(const float* __restrict__ yp, const float* __restrict__ be2,
                       float* __restrict__ y) {
  int idx = blockIdx.x * 256 + threadIdx.x;   // 65536
  int t = idx & 63, l = (idx >> 6) & 1, b = idx >> 7;
  float s = be2[l];
#pragma unroll
  for (int hb = 0; hb < 4; ++hb) s += yp[(((size_t)hb * Bz + b) * LATZ + l) * TT + t];
  y[idx] = s;
}

// Wd2 (f32 [k=1024][n=512]) -> bf16 MFMA A-fragment layout
__global__ void k_wd2t(const float* __restrict__ Wd2, unsigned short* __restrict__ at) {
  int s = blockIdx.x * 256 + threadIdx.x;     // 65536 slots
  int l = s & 63;
  int frag = s >> 6;
  int mf = frag & 31, kt = frag >> 5;
  int n = mf * 16 + (l & 15);
  int kbase = kt * 32 + (l >> 4) * 8;
  unsigned short v[8];
#pragma unroll
  for (int e = 0; e < 8; ++e) v[e] = f2bf(Wd2[(size_t)(kbase + e) * NF + n]);
  *(uint4*)(at + (size_t)s * 8) = pack8(v);
}

// hd B-fragment staging: 8 tanh -> one ds_write_b128 in frag order
__device__ __forceinline__ void stage_hd(int kt, unsigned short* dst, int q,
                                         float y0t, float y1t,
                                         const float* __restrict__ Wd1,
                                         const float* __restrict__ bd1) {
  int k = kt * 32 + q * 8;
  float4 w0a = *(const float4*)&Wd1[k];
  float4 w0b = *(const float4*)&Wd1[k + 4];
  float4 w1a = *(const float4*)&Wd1[HIDZ + k];
  float4 w1b = *(const float4*)&Wd1[HIDZ + k + 4];
  float4 ba  = *(const float4*)&bd1[k];
  float4 bb  = *(const float4*)&bd1[k + 4];
  float h[8];
  h[0] = tanhf(y0t * w0a.x + y1t * w1a.x + ba.x);
  h[1] = tanhf(y0t * w0a.y + y1t * w1a.y + ba.y);
  h[2] = tanhf(y0t * w0a.z + y1t * w1a.z + ba.z);
  h[3] = tanhf(y0t * w0a.w + y1t * w1a.w + ba.w);
  h[4] = tanhf(y0t * w0b.x + y1t * w1b.x + bb.x);
  h[5] = tanhf(y0t * w0b.y + y1t * w1b.y + bb.y);
  h[6] = tanhf(y0t * w0b.z + y1t * w1b.z + bb.z);
  h[7] = tanhf(y0t * w0b.w + y1t * w1b.w + bb.w);
  unsigned short hv[8];
#pragma unroll
  for (int e = 0; e < 8; ++e) hv[e] = f2bf(h[e]);
  *(uint4*)dst = pack8(hv);
}

// GEMM4 via MFMA 16x16x32 bf16 (verified layout). One block per b.
__global__ __launch_bounds__(256, 2) void k_gemm4m(const float* __restrict__ y,
                                                   const float* __restrict__ Wd1,
                                                   const float* __restrict__ bd1,
                                                   const unsigned short* __restrict__ at,
                                                   const float* __restrict__ bd2,
                                                   float* __restrict__ xae) {
  __shared__ __align__(16) unsigned short bbuf[2][4][64][8];
  __shared__ float ys[2][64];
  int b = blockIdx.x, tid = threadIdx.x;
  int w = tid >> 6, l = tid & 63;
  int c = l & 15, q = l >> 4;
  if (tid < 128) ys[tid >> 6][tid & 63] = y[((size_t)b * LATZ + (tid >> 6)) * TT + (tid & 63)];
  __syncthreads();
  int t_s = w * 16 + c;
  float y0t = ys[0][t_s], y1t = ys[1][t_s];
  f32x4 acc[8][4];
#pragma unroll
  for (int i = 0; i < 8; ++i)
#pragma unroll
    for (int j = 0; j < 4; ++j) acc[i][j] = (f32x4)(0.f);
  const bf16x8* A = (const bf16x8*)at;
  stage_hd(0, &bbuf[0][w][l][0], q, y0t, y1t, Wd1, bd1);
  for (int kt = 0; kt < 32; ++kt) {
    __syncthreads();
    if (kt + 1 < 32) stage_hd(kt + 1, &bbuf[(kt + 1) & 1][w][l][0], q, y0t, y1t, Wd1, bd1);
    bf16x8 bf[4];
#pragma unroll
    for (int t2 = 0; t2 < 4; ++t2) bf[t2] = *(const bf16x8*)&bbuf[kt & 1][t2][l][0];
    bf16x8 af[8];
#pragma unroll
    for (int mf = 0; mf < 8; ++mf) af[mf] = A[(size_t)((kt * 32 + w * 8 + mf) * 64) + l];
#pragma unroll
    for (int mf = 0; mf < 8; ++mf)
#pragma unroll
      for (int t2 = 0; t2 < 4; ++t2)
        acc[mf][t2] = __builtin_amdgcn_mfma_f32_16x16x32_bf16(af[mf], bf[t2], acc[mf][t2], 0, 0, 0);
  }
#pragma unroll
  for (int mf = 0; mf < 8; ++mf) {
    int nb = w * 128 + mf * 16 + q * 4;
#pragma unroll
    for (int r = 0; r < 4; ++r) {
      int n = nb + r;
      float bias = bd2[n];
#pragma unroll
      for (int t2 = 0; t2 < 4; ++t2)
        xae[((size_t)b * NF + n) * TT + t2 * 16 + c] = acc[mf][t2][r] + bias;
    }
  }
}

// G = Y-^T Y-  (63x63)
__global__ __launch_bounds__(1024) void k_G(const float* __restrict__ y, float* __restrict__ G) {
  __shared__ float ys[16][64];
  int tid = threadIdx.x;
  float acc[4] = {};
  for (int r0 = 0; r0 < 1024; r0 += 16) {
    __syncthreads();
    { int rr = tid >> 6, cc = tid & 63; ys[rr][cc] = y[(size_t)(r0 + rr) * 64 + cc]; }
    __syncthreads();
#pragma unroll
    for (int p = 0; p < 4; ++p) {
      int pair = tid + p * 1024;
      if (pair < 3969) {
        int i = pair / 63, j = pair % 63;
        float s = 0.f;
#pragma unroll
        for (int rr = 0; rr < 16; ++rr) s += ys[rr][i] * ys[rr][j];
        acc[p] += s;
      }
    }
  }
#pragma unroll
  for (int p = 0; p < 4; ++p) {
    int pair = tid + p * 1024;
    if (pair < 3969) G[pair] = acc[p];
  }
}

// Single-wave fully-register f32 Gauss-Jordan inverse of SPD 63x63.
// Lane i owns row i of [G|I] (126 f32 regs). Full unroll -> static reg indices;
// pivot-row broadcast via __shfl with compile-time lane. No LDS, no barriers.
__global__ __launch_bounds__(64, 1) void k_inv(const float* __restrict__ G,
                                               float* __restrict__ Ginv) {
  int i = threadIdx.x;
  float a[126];
  if (i < 63) {
#pragma unroll
    for (int j = 0; j < 63; ++j) a[j] = G[i * 63 + j];
  } else {
#pragma unroll
    for (int j = 0; j < 63; ++j) a[j] = (j == 0) ? 1.f : 0.f;  // dummy row, never read
  }
#pragma unroll
  for (int j = 0; j < 63; ++j) a[63 + j] = (i == j) ? 1.f : 0.f;
#pragma unroll
  for (int k = 0; k < 63; ++k) {
    float pivot = __shfl(a[k], k, 64);
    float rp = 1.f / pivot;
    float m = a[k];
    bool isk = (i == k);
#pragma unroll
    for (int j = k; j < 126; ++j) {
      float t = __shfl(a[j], k, 64) * rp;   // reads lane k's pre-update a[j]
      a[j] = isk ? t : (a[j] - m * t);
    }
  }
  if (i < 63) {
#pragma unroll
    for (int j = 0; j < 63; ++j) Ginv[i * 63 + j] = a[63 + j];
  }
}

// P = Ginv * Y-^T  (63 x 1024)
__global__ __launch_bounds__(256) void k_P(const float* __restrict__ y,
                                           const float* __restrict__ Ginv,
                                           float* __restrict__ P) {
  __shared__ float ys[64][65];
  int r0 = blockIdx.x * 64, tid = threadIdx.x;
#pragma unroll
  for (int p = 0; p < 16; ++p) {
    int f = tid + p * 256;
    ys[f >> 6][f & 63] = y[(size_t)(r0 + (f >> 6)) * 64 + (f & 63)];
  }
  __syncthreads();
#pragma unroll
  for (int p = 0; p < 16; ++p) {
    int o = tid + p * 256;
    if (o < 4032) {
      int i = o >> 6, rr = o & 63;
      float s = 0.f;
#pragma unroll
      for (int j = 0; j < 63; ++j) s += Ginv[i * 63 + j] * ys[rr][j];
      P[(size_t)i * 1024 + r0 + rr] = s;
    }
  }
}

// proj = I - P @ Y-
__global__ __launch_bounds__(1024) void k_proj(const float* __restrict__ y,
                                               const float* __restrict__ P,
                                               float* __restrict__ proj) {
  __shared__ float ys[16][64];
  __shared__ float ps[63][16];
  int tid = threadIdx.x;
  float acc[4] = {};
  for (int r0 = 0; r0 < 1024; r0 += 16) {
    __syncthreads();
    { int rr = tid >> 6, cc = tid & 63; ys[rr][cc] = y[(size_t)(r0 + rr) * 64 + cc]; }
    if (tid < 1008) { int i = tid >> 4, rr = tid & 15; ps[i][rr] = P[(size_t)i * 1024 + r0 + rr]; }
    __syncthreads();
#pragma unroll
    for (int p = 0; p < 4; ++p) {
      int pair = tid + p * 1024;
      if (pair < 3969) {
        int i = pair / 63, j = pair % 63;
        float s = 0.f;
#pragma unroll
        for (int rr = 0; rr < 16; ++rr) s += ps[i][rr] * ys[rr][j];
        acc[p] += s;
      }
    }
  }
#pragma unroll
  for (int p = 0; p < 4; ++p) {
    int pair = tid + p * 1024;
    if (pair < 3969) {
      int i = pair / 63, j = pair % 63;
      proj[pair] = ((i == j) ? 1.f : 0.f) - acc[p];
    }
  }
}

// Amat = Y+ @ P
__global__ __launch_bounds__(256) void k_Amat(const float* __restrict__ y,
                                              const float* __restrict__ P,
                                              float* __restrict__ amat_out,
                                              float* __restrict__ a_ws) {
  __shared__ float Yp[64][65];
  __shared__ float Ps[63][64];
  int r0 = blockIdx.x * 64, p0 = blockIdx.y * 64;
  int tid = threadIdx.x, tx = tid & 15, ty = tid >> 4;
#pragma unroll
  for (int p = 0; p < 16; ++p) {
    int f = tid + p * 256;
    Yp[f >> 6][f & 63] = y[(size_t)(p0 + (f >> 6)) * 64 + (f & 63)];
  }
#pragma unroll
  for (int p = 0; p < 16; ++p) {
    int f = tid + p * 256;
    if (f < 4032) {
      int j = f >> 6, rr = f & 63;
      Ps[j][rr] = P[(size_t)j * 1024 + r0 + rr];
    }
  }
  __syncthreads();
  float acc[4][4] = {};
  for (int j = 0; j < 63; ++j) {
    float a0 = Yp[ty * 4 + 0][j + 1];
    float a1 = Yp[ty * 4 + 1][j + 1];
    float a2 = Yp[ty * 4 + 2][j + 1];
    float a3 = Yp[ty * 4 + 3][j + 1];
    float4 bv = *(float4*)&Ps[j][tx * 4];
    acc[0][0] += a0 * bv.x; acc[0][1] += a0 * bv.y; acc[0][2] += a0 * bv.z; acc[0][3] += a0 * bv.w;
    acc[1][0] += a1 * bv.x; acc[1][1] += a1 * bv.y; acc[1][2] += a1 * bv.z; acc[1][3] += a1 * bv.w;
    acc[2][0] += a2 * bv.x; acc[2][1] += a2 * bv.y; acc[2][2] += a2 * bv.z; acc[2][3] += a2 * bv.w;
    acc[3][0] += a3 * bv.x; acc[3][1] += a3 * bv.y; acc[3][2] += a3 * bv.z; acc[3][3] += a3 * bv.w;
  }
#pragma unroll
  for (int i = 0; i < 4; ++i) {
#pragma unroll
    for (int jj = 0; jj < 4; ++jj) {
      size_t idx = (size_t)(p0 + ty * 4 + i) * 1024 + r0 + tx * 4 + jj;
      amat_out[idx] = acc[i][jj];
      a_ws[idx] = acc[i][jj];
    }
  }
}

// dmd_loss = sum((Y+ @ proj)^2)
__global__ __launch_bounds__(256) void k_dmdloss(const float* __restrict__ y,
                                                 const float* __restrict__ proj,
                                                 float* __restrict__ out_dmd) {
  __shared__ float ps[3969];
  int tid = threadIdx.x;
  for (int f = tid; f < 3969; f += 256) ps[f] = proj[f];
  __syncthreads();
  int p = blockIdx.x * 256 + tid;
  float yp[63];
#pragma unroll
  for (int k = 0; k < 63; ++k) yp[k] = y[(size_t)p * 64 + k + 1];
  float accv = 0.f;
  for (int j = 0; j < 63; ++j) {
    float s = 0.f;
#pragma unroll
    for (int k = 0; k < 63; ++k) s += yp[k] * ps[k * 63 + j];
    accv += s * s;
  }
  float tot = blockReduceSum(accv);
  if (tid == 0) atomicAdd(out_dmd, tot);
}

__global__ void k_y0(const float* __restrict__ y, float* __restrict__ v0) {
  int r = threadIdx.x + blockIdx.x * 1024;
  v0[r] = y[(size_t)r * 64];
}

// vout = A @ v; ypred[:, t] = vout; also M0[:, t] = vout (t<8)
__global__ __launch_bounds__(256) void k_matvec(const float* __restrict__ A,
                                                const float* __restrict__ v,
                                                float* __restrict__ vout,
                                                float* __restrict__ ypred,
                                                float* __restrict__ mcol, int t) {
  int tid = threadIdx.x;
  int ry = tid >> 4, cx = tid & 15;
  int r = blockIdx.x * 16 + ry;
  const float* Ar = A + (size_t)r * 1024;
  float s = 0.f;
  for (int c0 = cx * 4; c0 < 1024; c0 += 64) {
    float4 a = *(const float4*)&Ar[c0];
    float4 vv = *(const float4*)&v[c0];
    s += a.x * vv.x + a.y * vv.y + a.z * vv.z + a.w * vv.w;
  }
#pragma unroll
  for (int off = 8; off > 0; off >>= 1) s += __shfl_down(s, off, 16);
  if (cx == 0) {
    vout[r] = s;
    ypred[(size_t)r * 64 + t] = s;
    mcol[(size_t)r * 8 + t] = s;
  }
}

// C = X @ X (1024x1024) via split-bf16 3-pass MFMA, f32 in/out (operands L2-resident)
__global__ __launch_bounds__(256) void k_sq(const float* __restrict__ X, float* __restrict__ C) {
  int bm = blockIdx.y, bn = blockIdx.x;
  int tid = threadIdx.x, w = tid >> 6, l = tid & 63, q = l >> 4, c = l & 15;
  int mb = bm * 64 + (w >> 1) * 32, nb = bn * 64 + (w & 1) * 32;
  f32x4 acc[2][2];
#pragma unroll
  for (int i = 0; i < 2; ++i)
#pragma unroll
    for (int j = 0; j < 2; ++j) acc[i][j] = (f32x4)(0.f);
  for (int kt = 0; kt < 32; ++kt) {
    bf16x8 ah[2], al[2], bh[2], bl[2];
#pragma unroll
    for (int mf = 0; mf < 2; ++mf) {
      const float* xp = X + (size_t)(mb + mf * 16 + c) * 1024 + kt * 32 + q * 8;
      float v[8];
      *(float4*)&v[0] = *(const float4*)xp;
      *(float4*)&v[4] = *(const float4*)(xp + 4);
      split8(v, ah[mf], al[mf]);
    }
#pragma unroll
    for (int nf = 0; nf < 2; ++nf) {
      const float* xp = X + (size_t)(kt * 32 + q * 8) * 1024 + nb + nf * 16 + c;
      float v[8];
#pragma unroll
      for (int e = 0; e < 8; ++e) v[e] = xp[e * 1024];
      split8(v, bh[nf], bl[nf]);
    }
#pragma unroll
    for (int mf = 0; mf < 2; ++mf)
#pragma unroll
      for (int nf = 0; nf < 2; ++nf) {
        acc[mf][nf] = __builtin_amdgcn_mfma_f32_16x16x32_bf16(ah[mf], bh[nf], acc[mf][nf], 0, 0, 0);
        acc[mf][nf] = __builtin_amdgcn_mfma_f32_16x16x32_bf16(ah[mf], bl[nf], acc[mf][nf], 0, 0, 0);
        acc[mf][nf] = __builtin_amdgcn_mfma_f32_16x16x32_bf16(al[mf], bh[nf], acc[mf][nf], 0, 0, 0);
      }
  }
#pragma unroll
  for (int mf = 0; mf < 2; ++mf)
#pragma unroll
    for (int nf = 0; nf < 2; ++nf)
#pragma unroll
      for (int r = 0; r < 4; ++r)
        C[(size_t)(mb + mf * 16 + q * 4 + r) * 1024 + nb + nf * 16 + c] = acc[mf][nf][r];
}

// Mout = A8 @ Min (1024x8); ypred[:, tbase+j] = Mout[:, j]
__global__ __launch_bounds__(256) void k_bstep(const float* __restrict__ A8,
                                               const float* __restrict__ Min,
                                               float* __restrict__ Mout,
                                               float* __restrict__ ypred, int tbase) {
  __shared__ float m0[8][1024];
  int tid = threadIdx.x;
  for (int i = tid; i < 8192; i += 256) m0[i & 7][i >> 3] = Min[i];
  __syncthreads();
  int ry = tid >> 4, cx = tid & 15;
  int r = blockIdx.x * 16 + ry;
  const float* Ar = A8 + (size_t)r * 1024;
  float acc8[8] = {};
  for (int k0 = cx * 4; k0 < 1024; k0 += 64) {
    float4 a = *(const float4*)&Ar[k0];
#pragma unroll
    for (int kk = 0; kk < 4; ++kk) {
      float av = (&a.x)[kk];
      int k = k0 + kk;
#pragma unroll
      for (int j = 0; j < 8; ++j) acc8[j] += av * m0[j][k];
    }
  }
#pragma unroll
  for (int j = 0; j < 8; ++j) {
#pragma unroll
    for (int off = 8; off > 0; off >>= 1) acc8[j] += __shfl_xor(acc8[j], off, 16);
  }
  if (cx == 0) {
#pragma unroll
    for (int j = 0; j < 8; ++j) {
      Mout[(size_t)r * 8 + j] = acc8[j];
      ypred[(size_t)r * 64 + tbase + j] = acc8[j];
    }
  }
}

__global__ __launch_bounds__(256) void k_predloss(const float* __restrict__ y,
                                                  const float* __restrict__ ypred,
                                                  float* __restrict__ outp) {
  int i = blockIdx.x * 256 + threadIdx.x;
  float d = ypred[i] - y[i];
  float tot = blockReduceSum(d * d);
  if (threadIdx.x == 0) atomicAdd(outp, tot * (1.f / 65536.f));
}

__global__ __launch_bounds__(256) void k_aeloss(const float* __restrict__ x,
                                                const float* __restrict__ xae,
                                                float* __restrict__ outp) {
  int i = blockIdx.x * 256 + threadIdx.x;
  float d = x[(size_t)i * 64] - xae[(size_t)i * 64];
  float tot = blockReduceSum(d * d);
  if (threadIdx.x == 0) atomicAdd(outp, tot * (1.f / 262144.f));
}

extern "C" void kernel_launch(void* const* d_in, const int* in_sizes, int n_in,
                              void* d_out, int out_size, void* d_ws, size_t ws_size,
                              hipStream_t stream) {
  (void)in_sizes; (void)n_in; (void)out_size; (void)ws_size;
  const float* x   = (const float*)d_in[0];
  const float* We1 = (const float*)d_in[1];
  const float* be1 = (const float*)d_in[2];
  const float* We2 = (const float*)d_in[3];
  const float* be2 = (const float*)d_in[4];
  const float* Wd1 = (const float*)d_in[5];
  const float* bd1 = (const float*)d_in[6];
  const float* Wd2 = (const float*)d_in[7];
  const float* bd2 = (const float*)d_in[8];
  float* out = (float*)d_out;
  float* wsf = (float*)d_ws;

  float* y_out = out + OFF_Y;
  unsigned short* wd2t = (unsigned short*)(wsf + WS_WD2T);
  unsigned short* we1h = (unsigned short*)(wsf + WS_WE1H);
  unsigned short* we1l = (unsigned short*)(wsf + WS_WE1L);

  k_init<<<1, 64, 0, stream>>>(out + OFF_DMD, out + OFF_AE, out + OFF_PRED);
  k_we1t<<<256, 256, 0, stream>>>(We1, we1h, we1l);
  k_wd2t<<<256, 256, 0, stream>>>(Wd2, wd2t);
  k_gemm1m<<<2048, 256, 0, stream>>>(x, we1h, we1l, be1, We2, wsf + WS_YP);
  k_yred<<<256, 256, 0, stream>>>(wsf + WS_YP, be2, y_out);
  k_gemm4m<<<512, 256, 0, stream>>>(y_out, Wd1, bd1, wd2t, bd2, out + OFF_XAE);
  k_G<<<1, 1024, 0, stream>>>(y_out, wsf + WS_G);
  k_inv<<<1, 64, 0, stream>>>(wsf + WS_G, wsf + WS_GINV);
  k_P<<<16, 256, 0, stream>>>(y_out, wsf + WS_GINV, wsf + WS_P);
  k_proj<<<1, 1024, 0, stream>>>(y_out, wsf + WS_P, wsf + WS_PROJ);
  k_Amat<<<dim3(16, 16), 256, 0, stream>>>(y_out, wsf + WS_P, out + OFF_AMAT, wsf + WS_AM);
  k_dmdloss<<<4, 256, 0, stream>>>(y_out, wsf + WS_PROJ, out + OFF_DMD);
  // A^2, A^4, A^8
  k_sq<<<dim3(16, 16), 256, 0, stream>>>(wsf + WS_AM, wsf + WS_PW0);
  k_sq<<<dim3(16, 16), 256, 0, stream>>>(wsf + WS_PW0, wsf + WS_PW1);
  k_sq<<<dim3(16, 16), 256, 0, stream>>>(wsf + WS_PW1, wsf + WS_PW0);
  k_y0<<<1, 1024, 0, stream>>>(y_out, wsf + WS_V0);
  // u_j = A^j y0 = preds[0..7]
  for (int t = 0; t < 8; ++t) {
    const float* vin = wsf + ((t & 1) ? WS_V1 : WS_V0);
    float* vout = wsf + ((t & 1) ? WS_V0 : WS_V1);
    k_matvec<<<64, 256, 0, stream>>>(wsf + WS_AM, vin, vout, out + OFF_YPRED, wsf + WS_M0, t);
  }
  // M_a = A8 @ M_{a-1} = preds[8a .. 8a+7]
  for (int a = 1; a < 8; ++a) {
    const float* min = wsf + (((a - 1) & 1) ? WS_M1 : WS_M0);
    float* mout = wsf + ((a & 1) ? WS_M1 : WS_M0);
    k_bstep<<<64, 256, 0, stream>>>(wsf + WS_PW0, min, mout, out + OFF_YPRED, 8 * a);
  }
  k_predloss<<<256, 256, 0, stream>>>(y_out, out + OFF_YPRED, out + OFF_PRED);
  k_aeloss<<<1024, 256, 0, stream>>>(x, out + OFF_XAE, out + OFF_AE);
}

// Round 7
// 612.615 us; speedup vs baseline: 3.8628x; 1.7077x over previous
//
#include <hip/hip_runtime.h>
#include <hip/hip_bf16.h>

#define Bz 512
#define NF 512
#define TT 64
#define HIDZ 1024
#define LATZ 2

// output layout (floats)
static const size_t OFF_XAE   = 0;                                  // 512*512*64
static const size_t OFF_Y     = (size_t)Bz * NF * TT;               // 16777216
static const size_t OFF_DMD   = OFF_Y + (size_t)Bz * LATZ * TT;     // 16842752
static const size_t OFF_AE    = OFF_DMD + 1;                        // 16842753
static const size_t OFF_YPRED = OFF_AE + 1;                         // 16842754
static const size_t OFF_AMAT  = OFF_YPRED + (size_t)Bz * LATZ * TT; // 16908290
static const size_t OFF_PRED  = OFF_AMAT + (size_t)1024 * 1024;     // 17956866

// workspace layout (float offsets)
#define WS_G     0         // 63*63
#define WS_GINV  4096
#define WS_PROJ  8192
#define WS_P     16384     // 63*1024 -> ends 80896
#define WS_YP    1179648   // 4*512*2*64 y partials -> ends 1441792
#define WS_W     1441792   // 63*63
#define WS_GP    1445888   // 16*3969 partial G
#define WS_WP    1511424   // 16*3969 partial W
#define WS_PP    1576960   // 16*3969 partial P@Y-
#define WS_U     1642496   // 64*64 chain vectors (stride 64)
#define WS_WD2T  3538944   // 1 MB ushort: Wd2 bf16 A-frag layout -> ends 3801088
#define WS_WE1H  3801088   // 1 MB ushort: We1 hi A-frags -> ends 4063232
#define WS_WE1L  4063232   // 1 MB ushort: We1 lo A-frags -> ends 4325376

typedef __attribute__((ext_vector_type(8))) short bf16x8;
typedef __attribute__((ext_vector_type(4))) float f32x4;

__device__ __forceinline__ unsigned short f2bf(float f) {
  unsigned u = __float_as_uint(f);
  unsigned r = (u + 0x7fffu + ((u >> 16) & 1u)) >> 16;
  return (unsigned short)r;
}
__device__ __forceinline__ float bf2f(unsigned short h) {
  return __uint_as_float((unsigned)h << 16);
}
__device__ __forceinline__ uint4 pack8(const unsigned short* v) {
  return make_uint4((unsigned)v[0] | ((unsigned)v[1] << 16),
                    (unsigned)v[2] | ((unsigned)v[3] << 16),
                    (unsigned)v[4] | ((unsigned)v[5] << 16),
                    (unsigned)v[6] | ((unsigned)v[7] << 16));
}
__device__ __forceinline__ void split8(const float* v, bf16x8& hi, bf16x8& lo) {
#pragma unroll
  for (int e = 0; e < 8; ++e) {
    unsigned short h = f2bf(v[e]);
    hi[e] = (short)h;
    lo[e] = (short)f2bf(v[e] - bf2f(h));
  }
}

__device__ inline float blockReduceSum(float v) {
  __shared__ float sh[16];
  int lane = threadIdx.x & 63;
  int wid  = threadIdx.x >> 6;
#pragma unroll
  for (int off = 32; off > 0; off >>= 1) v += __shfl_down(v, off, 64);
  if (lane == 0) sh[wid] = v;
  __syncthreads();
  int nw = blockDim.x >> 6;
  v = (threadIdx.x < (unsigned)nw) ? sh[threadIdx.x] : 0.f;
  if (wid == 0) {
#pragma unroll
    for (int off = 8; off > 0; off >>= 1) v += __shfl_down(v, off, 64);
  }
  return v;
}

__global__ void k_init(float* dmd, float* ae, float* pred) {
  if (threadIdx.x == 0) { *dmd = 0.f; *ae = 0.f; *pred = 0.f; }
}

// We1 [k=512][m=1024] -> A-frag hi/lo
__global__ void k_we1t(const float* __restrict__ We1,
                       unsigned short* __restrict__ ah, unsigned short* __restrict__ al) {
  int s = blockIdx.x * 256 + threadIdx.x;   // 65536 slots
  int l = s & 63, mfg = (s >> 6) & 63, kt = s >> 12;
  int m = mfg * 16 + (l & 15);
  int k0 = kt * 32 + (l >> 4) * 8;
  unsigned short h[8], lo[8];
#pragma unroll
  for (int e = 0; e < 8; ++e) {
    float v = We1[(size_t)(k0 + e) * HIDZ + m];
    h[e] = f2bf(v);
    lo[e] = f2bf(v - bf2f(h[e]));
  }
  *(uint4*)(ah + (size_t)s * 8) = pack8(h);
  *(uint4*)(al + (size_t)s * 8) = pack8(lo);
}

// GEMM1 via split-bf16 3-pass MFMA. Block: 256h x 64t for one b.
__global__ __launch_bounds__(256, 2) void k_gemm1m(const float* __restrict__ x,
    const unsigned short* __restrict__ we1h, const unsigned short* __restrict__ we1l,
    const float* __restrict__ be1, const float* __restrict__ We2,
    float* __restrict__ ypartial) {
  __shared__ uint4 bh4[4][64], bl4[4][64];
  __shared__ float yredl[4][2][64];
  int o = blockIdx.x;
  int lbid = (o & 7) * 256 + (o >> 3);
  int b = lbid >> 2, hb = lbid & 3;
  int tid = threadIdx.x, w = tid >> 6, l = tid & 63, q = l >> 4, c = l & 15;
  const float* xb = x + (size_t)b * NF * TT;
  f32x4 acc[4][4];
#pragma unroll
  for (int i = 0; i < 4; ++i)
#pragma unroll
    for (int j = 0; j < 4; ++j) acc[i][j] = (f32x4)(0.f);
  for (int kt = 0; kt < 16; ++kt) {
    {
      const float* xp = xb + (size_t)(kt * 32 + q * 8) * TT + (w * 16 + c);
      float v[8];
#pragma unroll
      for (int e = 0; e < 8; ++e) v[e] = xp[e * TT];
      unsigned short h[8], lo[8];
#pragma unroll
      for (int e = 0; e < 8; ++e) {
        h[e] = f2bf(v[e]);
        lo[e] = f2bf(v[e] - bf2f(h[e]));
      }
      bh4[w][l] = pack8(h);
      bl4[w][l] = pack8(lo);
    }
    __syncthreads();
    bf16x8 ah[4], al[4], bhf[4], blf[4];
#pragma unroll
    for (int mf = 0; mf < 4; ++mf) {
      size_t slot = ((size_t)kt * 64 + hb * 16 + w * 4 + mf) * 64 + l;
      ah[mf] = *(const bf16x8*)(we1h + slot * 8);
      al[mf] = *(const bf16x8*)(we1l + slot * 8);
    }
#pragma unroll
    for (int nf = 0; nf < 4; ++nf) {
      bhf[nf] = *(bf16x8*)&bh4[nf][l];
      blf[nf] = *(bf16x8*)&bl4[nf][l];
    }
#pragma unroll
    for (int mf = 0; mf < 4; ++mf)
#pragma unroll
      for (int nf = 0; nf < 4; ++nf) {
        acc[mf][nf] = __builtin_amdgcn_mfma_f32_16x16x32_bf16(ah[mf], bhf[nf], acc[mf][nf], 0, 0, 0);
        acc[mf][nf] = __builtin_amdgcn_mfma_f32_16x16x32_bf16(ah[mf], blf[nf], acc[mf][nf], 0, 0, 0);
        acc[mf][nf] = __builtin_amdgcn_mfma_f32_16x16x32_bf16(al[mf], bhf[nf], acc[mf][nf], 0, 0, 0);
      }
    __syncthreads();
  }
  float p0[4] = {0.f, 0.f, 0.f, 0.f}, p1[4] = {0.f, 0.f, 0.f, 0.f};
#pragma unroll
  for (int mf = 0; mf < 4; ++mf) {
    int hbase = hb * 256 + w * 64 + mf * 16 + q * 4;
#pragma unroll
    for (int r = 0; r < 4; ++r) {
      int hh = hbase + r;
      float bias = be1[hh];
      float w20 = We2[2 * hh], w21 = We2[2 * hh + 1];
#pragma unroll
      for (int nf = 0; nf < 4; ++nf) {
        float hv = tanhf(acc[mf][nf][r] + bias);
        p0[nf] += hv * w20;
        p1[nf] += hv * w21;
      }
    }
  }
#pragma unroll
  for (int nf = 0; nf < 4; ++nf) {
    p0[nf] += __shfl_xor(p0[nf], 16, 64); p0[nf] += __shfl_xor(p0[nf], 32, 64);
    p1[nf] += __shfl_xor(p1[nf], 16, 64); p1[nf] += __shfl_xor(p1[nf], 32, 64);
  }
  if (q == 0) {
#pragma unroll
    for (int nf = 0; nf < 4; ++nf) {
      yredl[w][0][nf * 16 + c] = p0[nf];
      yredl[w][1][nf * 16 + c] = p1[nf];
    }
  }
  __syncthreads();
  if (tid < 128) {
    int lat = tid >> 6, t = tid & 63;
    float s = yredl[0][lat][t] + yredl[1][lat][t] + yredl[2][lat][t] + yredl[3][lat][t];
    ypartial[(((size_t)hb * Bz + b) * LATZ + lat) * TT + t] = s;
  }
}

// y = be2 + sum of 4 h-block partials (fixed order)
__global__ void k_yred(const float* __restrict__ yp, const float* __restrict__ be2,
                       float* __restrict__ y) {
  int idx = blockIdx.x * 256 + threadIdx.x;   // 65536
  int t = idx & 63, l = (idx >> 6) & 1, b = idx >> 7;
  float s = be2[l];
#pragma unroll
  for (int hb = 0; hb < 4; ++hb) s += yp[(((size_t)hb * Bz + b) * LATZ + l) * TT + t];
  y[idx] = s;
}

// Wd2 (f32 [k=1024][n=512]) -> bf16 MFMA A-fragment layout
__global__ void k_wd2t(const float* __restrict__ Wd2, unsigned short* __restrict__ at) {
  int s = blockIdx.x * 256 + threadIdx.x;     // 65536 slots
  int l = s & 63;
  int frag = s >> 6;
  int mf = frag & 31, kt = frag >> 5;
  int n = mf * 16 + (l & 15);
  int kbase = kt * 32 + (l >> 4) * 8;
  unsigned short v[8];
#pragma unroll
  for (int e = 0; e < 8; ++e) v[e] = f2bf(Wd2[(size_t)(kbase + e) * NF + n]);
  *(uint4*)(at + (size_t)s * 8) = pack8(v);
}

__device__ __forceinline__ void stage_hd(int kt, unsigned short* dst, int q,
                                         float y0t, float y1t,
                                         const float* __restrict__ Wd1,
                                         const float* __restrict__ bd1) {
  int k = kt * 32 + q * 8;
  float4 w0a = *(const float4*)&Wd1[k];
  float4 w0b = *(const float4*)&Wd1[k + 4];
  float4 w1a = *(const float4*)&Wd1[HIDZ + k];
  float4 w1b = *(const float4*)&Wd1[HIDZ + k + 4];
  float4 ba  = *(const float4*)&bd1[k];
  float4 bb  = *(const float4*)&bd1[k + 4];
  float h[8];
  h[0] = tanhf(y0t * w0a.x + y1t * w1a.x + ba.x);
  h[1] = tanhf(y0t * w0a.y + y1t * w1a.y + ba.y);
  h[2] = tanhf(y0t * w0a.z + y1t * w1a.z + ba.z);
  h[3] = tanhf(y0t * w0a.w + y1t * w1a.w + ba.w);
  h[4] = tanhf(y0t * w0b.x + y1t * w1b.x + bb.x);
  h[5] = tanhf(y0t * w0b.y + y1t * w1b.y + bb.y);
  h[6] = tanhf(y0t * w0b.z + y1t * w1b.z + bb.z);
  h[7] = tanhf(y0t * w0b.w + y1t * w1b.w + bb.w);
  unsigned short hv[8];
#pragma unroll
  for (int e = 0; e < 8; ++e) hv[e] = f2bf(h[e]);
  *(uint4*)dst = pack8(hv);
}

// GEMM4 via MFMA 16x16x32 bf16. One block per b.
__global__ __launch_bounds__(256, 2) void k_gemm4m(const float* __restrict__ y,
                                                   const float* __restrict__ Wd1,
                                                   const float* __restrict__ bd1,
                                                   const unsigned short* __restrict__ at,
                                                   const float* __restrict__ bd2,
                                                   float* __restrict__ xae) {
  __shared__ __align__(16) unsigned short bbuf[2][4][64][8];
  __shared__ float ys[2][64];
  int b = blockIdx.x, tid = threadIdx.x;
  int w = tid >> 6, l = tid & 63;
  int c = l & 15, q = l >> 4;
  if (tid < 128) ys[tid >> 6][tid & 63] = y[((size_t)b * LATZ + (tid >> 6)) * TT + (tid & 63)];
  __syncthreads();
  int t_s = w * 16 + c;
  float y0t = ys[0][t_s], y1t = ys[1][t_s];
  f32x4 acc[8][4];
#pragma unroll
  for (int i = 0; i < 8; ++i)
#pragma unroll
    for (int j = 0; j < 4; ++j) acc[i][j] = (f32x4)(0.f);
  const bf16x8* A = (const bf16x8*)at;
  stage_hd(0, &bbuf[0][w][l][0], q, y0t, y1t, Wd1, bd1);
  for (int kt = 0; kt < 32; ++kt) {
    __syncthreads();
    if (kt + 1 < 32) stage_hd(kt + 1, &bbuf[(kt + 1) & 1][w][l][0], q, y0t, y1t, Wd1, bd1);
    bf16x8 bf[4];
#pragma unroll
    for (int t2 = 0; t2 < 4; ++t2) bf[t2] = *(const bf16x8*)&bbuf[kt & 1][t2][l][0];
    bf16x8 af[8];
#pragma unroll
    for (int mf = 0; mf < 8; ++mf) af[mf] = A[(size_t)((kt * 32 + w * 8 + mf) * 64) + l];
#pragma unroll
    for (int mf = 0; mf < 8; ++mf)
#pragma unroll
      for (int t2 = 0; t2 < 4; ++t2)
        acc[mf][t2] = __builtin_amdgcn_mfma_f32_16x16x32_bf16(af[mf], bf[t2], acc[mf][t2], 0, 0, 0);
  }
#pragma unroll
  for (int mf = 0; mf < 8; ++mf) {
    int nb = w * 128 + mf * 16 + q * 4;
#pragma unroll
    for (int r = 0; r < 4; ++r) {
      int n = nb + r;
      float bias = bd2[n];
#pragma unroll
      for (int t2 = 0; t2 < 4; ++t2)
        xae[((size_t)b * NF + n) * TT + t2 * 16 + c] = acc[mf][t2][r] + bias;
    }
  }
}

// Chunked G = Y-^T Y- and W = Y-^T Y+ partials. Block cb handles rows [cb*64, cb*64+64)
__global__ __launch_bounds__(256) void k_Gall(const float* __restrict__ y,
                                              float* __restrict__ Gp, float* __restrict__ Wp) {
  __shared__ float ys[64][65];
  int cb = blockIdx.x, tid = threadIdx.x;
#pragma unroll
  for (int p = 0; p < 16; ++p) {
    int f = tid + p * 256;
    int rr = f >> 6, cc = f & 63;
    ys[rr][cc] = y[(size_t)(cb * 64 + rr) * 64 + cc];
  }
  __syncthreads();
#pragma unroll
  for (int p = 0; p < 16; ++p) {
    int o = tid + p * 256;
    if (o < 3969) {
      int i = o / 63, j = o % 63;
      float gs = 0.f, wsv = 0.f;
#pragma unroll
      for (int rr = 0; rr < 64; ++rr) {
        float yi = ys[rr][i];
        gs  += yi * ys[rr][j];
        wsv += yi * ys[rr][j + 1];
      }
      Gp[cb * 3969 + o] = gs;
      Wp[cb * 3969 + o] = wsv;
    }
  }
}

// G, W = fixed-order sum of 16 partials
__global__ void k_Gred(const float* __restrict__ Gp, const float* __restrict__ Wp,
                       float* __restrict__ G, float* __restrict__ W) {
  int idx = blockIdx.x * 256 + threadIdx.x;   // 8192 threads
  if (idx >= 2 * 3969) return;
  int sel = idx >= 3969;
  int o = idx - sel * 3969;
  const float* src = sel ? Wp : Gp;
  float s = 0.f;
#pragma unroll
  for (int cb = 0; cb < 16; ++cb) s += src[cb * 3969 + o];
  (sel ? W : G)[o] = s;
}

// Single-wave fully-register f32 Gauss-Jordan inverse of SPD 63x63.
__global__ __launch_bounds__(64, 1) void k_inv(const float* __restrict__ G,
                                               float* __restrict__ Ginv) {
  int i = threadIdx.x;
  float a[126];
  if (i < 63) {
#pragma unroll
    for (int j = 0; j < 63; ++j) a[j] = G[i * 63 + j];
  } else {
#pragma unroll
    for (int j = 0; j < 63; ++j) a[j] = (j == 0) ? 1.f : 0.f;
  }
#pragma unroll
  for (int j = 0; j < 63; ++j) a[63 + j] = (i == j) ? 1.f : 0.f;
#pragma unroll
  for (int k = 0; k < 63; ++k) {
    float pivot = __shfl(a[k], k, 64);
    float rp = 1.f / pivot;
    float m = a[k];
    bool isk = (i == k);
#pragma unroll
    for (int j = k; j < 126; ++j) {
      float t = __shfl(a[j], k, 64) * rp;
      a[j] = isk ? t : (a[j] - m * t);
    }
  }
  if (i < 63) {
#pragma unroll
    for (int j = 0; j < 63; ++j) Ginv[i * 63 + j] = a[63 + j];
  }
}

// P = Ginv * Y-^T  (63 x 1024)
__global__ __launch_bounds__(256) void k_P(const float* __restrict__ y,
                                           const float* __restrict__ Ginv,
                                           float* __restrict__ P) {
  __shared__ float ys[64][65];
  int r0 = blockIdx.x * 64, tid = threadIdx.x;
#pragma unroll
  for (int p = 0; p < 16; ++p) {
    int f = tid + p * 256;
    ys[f >> 6][f & 63] = y[(size_t)(r0 + (f >> 6)) * 64 + (f & 63)];
  }
  __syncthreads();
#pragma unroll
  for (int p = 0; p < 16; ++p) {
    int o = tid + p * 256;
    if (o < 4032) {
      int i = o >> 6, rr = o & 63;
      float s = 0.f;
#pragma unroll
      for (int j = 0; j < 63; ++j) s += Ginv[i * 63 + j] * ys[rr][j];
      P[(size_t)i * 1024 + r0 + rr] = s;
    }
  }
}

// Chunked (P @ Y-) partials. Block cb handles K rows [cb*64, cb*64+64)
__global__ __launch_bounds__(256) void k_projc(const float* __restrict__ y,
                                               const float* __restrict__ P,
                                               float* __restrict__ Pp) {
  __shared__ float ps[63][64];
  __shared__ float ysm[64][65];
  int cb = blockIdx.x, tid = threadIdx.x;
#pragma unroll
  for (int p = 0; p < 16; ++p) {
    int f = tid + p * 256;
    if (f < 4032) {
      int i = f >> 6, rr = f & 63;
      ps[i][rr] = P[(size_t)i * 1024 + cb * 64 + rr];
    }
    int rr2 = f >> 6, cc = f & 63;
    ysm[rr2][cc] = y[(size_t)(cb * 64 + rr2) * 64 + cc];
  }
  __syncthreads();
#pragma unroll
  for (int p = 0; p < 16; ++p) {
    int o = tid + p * 256;
    if (o < 3969) {
      int i = o / 63, j = o % 63;
      float s = 0.f;
#pragma unroll
      for (int rr = 0; rr < 64; ++rr) s += ps[i][rr] * ysm[rr][j];
      Pp[cb * 3969 + o] = s;
    }
  }
}

// proj = I - fixed-order sum of partials
__global__ void k_projred(const float* __restrict__ Pp, float* __restrict__ proj) {
  int o = blockIdx.x * 256 + threadIdx.x;
  if (o >= 3969) return;
  int i = o / 63, j = o % 63;
  float s = 0.f;
#pragma unroll
  for (int cb = 0; cb < 16; ++cb) s += Pp[cb * 3969 + o];
  proj[o] = ((i == j) ? 1.f : 0.f) - s;
}

// Amat = Y+ @ P
__global__ __launch_bounds__(256) void k_Amat(const float* __restrict__ y,
                                              const float* __restrict__ P,
                                              float* __restrict__ amat_out) {
  __shared__ float Yp[64][65];
  __shared__ float Ps[63][64];
  int r0 = blockIdx.x * 64, p0 = blockIdx.y * 64;
  int tid = threadIdx.x, tx = tid & 15, ty = tid >> 4;
#pragma unroll
  for (int p = 0; p < 16; ++p) {
    int f = tid + p * 256;
    Yp[f >> 6][f & 63] = y[(size_t)(p0 + (f >> 6)) * 64 + (f & 63)];
  }
#pragma unroll
  for (int p = 0; p < 16; ++p) {
    int f = tid + p * 256;
    if (f < 4032) {
      int j = f >> 6, rr = f & 63;
      Ps[j][rr] = P[(size_t)j * 1024 + r0 + rr];
    }
  }
  __syncthreads();
  float acc[4][4] = {};
  for (int j = 0; j < 63; ++j) {
    float a0 = Yp[ty * 4 + 0][j + 1];
    float a1 = Yp[ty * 4 + 1][j + 1];
    float a2 = Yp[ty * 4 + 2][j + 1];
    float a3 = Yp[ty * 4 + 3][j + 1];
    float4 bv = *(float4*)&Ps[j][tx * 4];
    acc[0][0] += a0 * bv.x; acc[0][1] += a0 * bv.y; acc[0][2] += a0 * bv.z; acc[0][3] += a0 * bv.w;
    acc[1][0] += a1 * bv.x; acc[1][1] += a1 * bv.y; acc[1][2] += a1 * bv.z; acc[1][3] += a1 * bv.w;
    acc[2][0] += a2 * bv.x; acc[2][1] += a2 * bv.y; acc[2][2] += a2 * bv.z; acc[2][3] += a2 * bv.w;
    acc[3][0] += a3 * bv.x; acc[3][1] += a3 * bv.y; acc[3][2] += a3 * bv.z; acc[3][3] += a3 * bv.w;
  }
#pragma unroll
  for (int i = 0; i < 4; ++i) {
#pragma unroll
    for (int jj = 0; jj < 4; ++jj) {
      size_t idx = (size_t)(p0 + ty * 4 + i) * 1024 + r0 + tx * 4 + jj;
      amat_out[idx] = acc[i][jj];
    }
  }
}

// dmd_loss = sum((Y+ @ proj)^2)
__global__ __launch_bounds__(256) void k_dmdloss(const float* __restrict__ y,
                                                 const float* __restrict__ proj,
                                                 float* __restrict__ out_dmd) {
  __shared__ float ps[3969];
  int tid = threadIdx.x;
  for (int f = tid; f < 3969; f += 256) ps[f] = proj[f];
  __syncthreads();
  int p = blockIdx.x * 256 + tid;
  float yp[63];
#pragma unroll
  for (int k = 0; k < 63; ++k) yp[k] = y[(size_t)p * 64 + k + 1];
  float accv = 0.f;
  for (int j = 0; j < 63; ++j) {
    float s = 0.f;
#pragma unroll
    for (int k = 0; k < 63; ++k) s += yp[k] * ps[k * 63 + j];
    accv += s * s;
  }
  float tot = blockReduceSum(accv);
  if (tid == 0) atomicAdd(out_dmd, tot);
}

// 63-dim power chain: M = Ginv*W (rows in regs), u_{t+1} = M u_t, u_0 = Ginv*G[:,0].
// Writes U[t*64 + i] = u_t[i]. Single wave, register-resident.
__global__ __launch_bounds__(64, 1) void k_chain(const float* __restrict__ G,
                                                 const float* __restrict__ W,
                                                 const float* __restrict__ Ginv,
                                                 float* __restrict__ U) {
  __shared__ float wl[63][64];
  __shared__ float zl[64];
  __shared__ float ul[64];
  int i = threadIdx.x;
  float g[63];
  if (i < 63) {
#pragma unroll
    for (int k = 0; k < 63; ++k) g[k] = Ginv[i * 63 + k];
    for (int k = 0; k < 63; ++k) wl[k][i] = W[k * 63 + i];
    zl[i] = G[i * 63];             // z0[i] = G[i][0] since y0 is column 0 of Y-
  } else {
#pragma unroll
    for (int k = 0; k < 63; ++k) g[k] = 0.f;
  }
  __syncthreads();
  float m[63];
#pragma unroll
  for (int j = 0; j < 63; ++j) {
    float s = 0.f;
#pragma unroll
    for (int k = 0; k < 63; ++k) s += g[k] * wl[k][j];
    m[j] = s;
  }
  float u = 0.f;
#pragma unroll
  for (int k = 0; k < 63; ++k) u += g[k] * zl[k];
  for (int t = 0; t < 64; ++t) {
    if (i < 63) U[t * 64 + i] = u;
    ul[i] = u;
    __syncthreads();
    float un = 0.f;
#pragma unroll
    for (int j = 0; j < 63; ++j) un += m[j] * ul[j];
    __syncthreads();
    u = un;
  }
}

// y_pred[r, t] = sum_j Y+[r][j] * U[t][j]
__global__ __launch_bounds__(256) void k_ypred(const float* __restrict__ y,
                                               const float* __restrict__ U,
                                               float* __restrict__ ypred) {
  __shared__ float yp[64][65];
  __shared__ float ul[64][65];
  int rb = blockIdx.x, tid = threadIdx.x;
#pragma unroll
  for (int p = 0; p < 16; ++p) {
    int f = tid + p * 256;
    int a = f >> 6, b2 = f & 63;
    yp[a][b2] = y[(size_t)(rb * 64 + a) * 64 + b2];
    ul[a][b2] = U[a * 64 + b2];
  }
  __syncthreads();
  int rr = tid >> 2, tg = tid & 3;
  float acc[16] = {};
  for (int j = 0; j < 63; ++j) {
    float yv = yp[rr][j + 1];
#pragma unroll
    for (int tt = 0; tt < 16; ++tt) acc[tt] += yv * ul[tg * 16 + tt][j];
  }
  float* op = ypred + (size_t)(rb * 64 + rr) * 64 + tg * 16;
#pragma unroll
  for (int e = 0; e < 8; ++e)
    *(float2*)&op[e * 2] = make_float2(acc[2 * e], acc[2 * e + 1]);
}

__global__ __launch_bounds__(256) void k_predloss(const float* __restrict__ y,
                                                  const float* __restrict__ ypred,
                                                  float* __restrict__ outp) {
  int i = blockIdx.x * 256 + threadIdx.x;
  float d = ypred[i] - y[i];
  float tot = blockReduceSum(d * d);
  if (threadIdx.x == 0) atomicAdd(outp, tot * (1.f / 65536.f));
}

__global__ __launch_bounds__(256) void k_aeloss(const float* __restrict__ x,
                                                const float* __restrict__ xae,
                                                float* __restrict__ outp) {
  int i = blockIdx.x * 256 + threadIdx.x;
  float d = x[(size_t)i * 64] - xae[(size_t)i * 64];
  float tot = blockReduceSum(d * d);
  if (threadIdx.x == 0) atomicAdd(outp, tot * (1.f / 262144.f));
}

extern "C" void kernel_launch(void* const* d_in, const int* in_sizes, int n_in,
                              void* d_out, int out_size, void* d_ws, size_t ws_size,
                              hipStream_t stream) {
  (void)in_sizes; (void)n_in; (void)out_size; (void)ws_size;
  const float* x   = (const float*)d_in[0];
  const float* We1 = (const float*)d_in[1];
  const float* be1 = (const float*)d_in[2];
  const float* We2 = (const float*)d_in[3];
  const float* be2 = (const float*)d_in[4];
  const float* Wd1 = (const float*)d_in[5];
  const float* bd1 = (const float*)d_in[6];
  const float* Wd2 = (const float*)d_in[7];
  const float* bd2 = (const float*)d_in[8];
  float* out = (float*)d_out;
  float* wsf = (float*)d_ws;

  float* y_out = out + OFF_Y;
  unsigned short* wd2t = (unsigned short*)(wsf + WS_WD2T);
  unsigned short* we1h = (unsigned short*)(wsf + WS_WE1H);
  unsigned short* we1l = (unsigned short*)(wsf + WS_WE1L);

  k_init<<<1, 64, 0, stream>>>(out + OFF_DMD, out + OFF_AE, out + OFF_PRED);
  k_we1t<<<256, 256, 0, stream>>>(We1, we1h, we1l);
  k_wd2t<<<256, 256, 0, stream>>>(Wd2, wd2t);
  k_gemm1m<<<2048, 256, 0, stream>>>(x, we1h, we1l, be1, We2, wsf + WS_YP);
  k_yred<<<256, 256, 0, stream>>>(wsf + WS_YP, be2, y_out);
  k_gemm4m<<<512, 256, 0, stream>>>(y_out, Wd1, bd1, wd2t, bd2, out + OFF_XAE);
  k_Gall<<<16, 256, 0, stream>>>(y_out, wsf + WS_GP, wsf + WS_WP);
  k_Gred<<<32, 256, 0, stream>>>(wsf + WS_GP, wsf + WS_WP, wsf + WS_G, wsf + WS_W);
  k_inv<<<1, 64, 0, stream>>>(wsf + WS_G, wsf + WS_GINV);
  k_chain<<<1, 64, 0, stream>>>(wsf + WS_G, wsf + WS_W, wsf + WS_GINV, wsf + WS_U);
  k_P<<<16, 256, 0, stream>>>(y_out, wsf + WS_GINV, wsf + WS_P);
  k_projc<<<16, 256, 0, stream>>>(y_out, wsf + WS_P, wsf + WS_PP);
  k_projred<<<16, 256, 0, stream>>>(wsf + WS_PP, wsf + WS_PROJ);
  k_Amat<<<dim3(16, 16), 256, 0, stream>>>(y_out, wsf + WS_P, out + OFF_AMAT);
  k_dmdloss<<<4, 256, 0, stream>>>(y_out, wsf + WS_PROJ, out + OFF_DMD);
  k_ypred<<<16, 256, 0, stream>>>(y_out, wsf + WS_U, out + OFF_YPRED);
  k_predloss<<<256, 256, 0, stream>>>(y_out, out + OFF_YPRED, out + OFF_PRED);
  k_aeloss<<<1024, 256, 0, stream>>>(x, out + OFF_XAE, out + OFF_AE);
}